// Round 1
// baseline (764.649 us; speedup 1.0000x reference)
//
#include <hip/hip_runtime.h>
#include <math.h>

#define D_MODEL 256
#define B_SZ 8
#define T_SZ 1024
#define NH 4
#define HD 64
#define MROWS (B_SZ * T_SZ)  // 8192

constexpr size_t S_ELT = (size_t)MROWS * D_MODEL;  // 2,097,152

// workspace layout (float offsets)
constexpr size_t OFF_R0 = 0;                 // 3S: qkv, then combined; later f = [0,4S)
constexpr size_t OFF_R1 = 3 * S_ELT;         // S: attn_out -> deltas -> states
constexpr size_t OFF_R2 = 4 * S_ELT;         // S: x (post-LN1), live to the end
constexpr size_t OFF_R3 = 5 * S_ELT;         // 2S: attn_raw -> h -> ffn_in -> ffn_out
constexpr size_t OFF_SCR1 = 7 * S_ELT;       // 65536: EMA chunk scratch
constexpr size_t OFF_SCR2 = OFF_SCR1 + 65536;// 65536: cumsum chunk scratch

// ---------------------------------------------------------------------------
// Generic fp32 GEMM: C[m][n] = epi( sum_k A[m][k] * W[n][k] + bias[n] )
// W row-major [N][K] (PyTorch/JAX 'oi' layout). 64x64 tile, BK=16, 4x4/thread.
// ---------------------------------------------------------------------------
enum { EPI_NONE = 0, EPI_GELU = 1, EPI_ADDSCALE = 2 };

template <int EPI>
__global__ __launch_bounds__(256)
void gemm_kernel(const float* __restrict__ A, int lda,
                 const float* __restrict__ W, int K,
                 const float* __restrict__ bias,
                 float* __restrict__ C, int ldc, int col_off,
                 const float* __restrict__ addsrc, int ld_add) {
  __shared__ float As[16][68];
  __shared__ float Bs[16][68];
  const int tid = threadIdx.x;
  const int m0 = blockIdx.x * 64;
  const int n0 = blockIdx.y * 64;
  const int tr = tid >> 4, tc = tid & 15;
  const int row4 = tr * 4, col4 = tc * 4;
  const int lrow = tid >> 2, lk = (tid & 3) * 4;
  float acc[4][4] = {};

  const float* Aptr = A + (size_t)(m0 + lrow) * lda + lk;
  const float* Wptr = W + (size_t)(n0 + lrow) * K + lk;

  for (int k0 = 0; k0 < K; k0 += 16) {
    float4 av = *(const float4*)(Aptr + k0);
    float4 wv = *(const float4*)(Wptr + k0);
    As[lk + 0][lrow] = av.x; As[lk + 1][lrow] = av.y;
    As[lk + 2][lrow] = av.z; As[lk + 3][lrow] = av.w;
    Bs[lk + 0][lrow] = wv.x; Bs[lk + 1][lrow] = wv.y;
    Bs[lk + 2][lrow] = wv.z; Bs[lk + 3][lrow] = wv.w;
    __syncthreads();
#pragma unroll
    for (int k = 0; k < 16; ++k) {
      float4 a4 = *(const float4*)&As[k][row4];
      float4 b4 = *(const float4*)&Bs[k][col4];
      float aa[4] = {a4.x, a4.y, a4.z, a4.w};
      float bb[4] = {b4.x, b4.y, b4.z, b4.w};
#pragma unroll
      for (int i = 0; i < 4; ++i)
#pragma unroll
        for (int j = 0; j < 4; ++j) acc[i][j] = fmaf(aa[i], bb[j], acc[i][j]);
    }
    __syncthreads();
  }

#pragma unroll
  for (int i = 0; i < 4; ++i) {
    const int m = m0 + row4 + i;
    float* op = C + (size_t)m * ldc + col_off + n0 + col4;
    float4 o;
#pragma unroll
    for (int j = 0; j < 4; ++j) {
      float v = acc[i][j] + bias[n0 + col4 + j];
      if (EPI == EPI_GELU) v = 0.5f * v * (1.0f + erff(v * 0.70710678118654752f));
      if (EPI == EPI_ADDSCALE)
        v = addsrc[(size_t)m * ld_add + n0 + col4 + j] + 0.3f * v;
      (&o.x)[j] = v;
    }
    *(float4*)op = o;
  }
}

// ---------------------------------------------------------------------------
// Flash attention: one block = (b, h, 64 q rows). hd=64, causal, scale=1/8.
// qkv layout: [B,T,3*D]; q at col h*64, k at D + h*64, v at 2D + h*64.
// out: [B,T,D] with D index = h*64 + d.
// ---------------------------------------------------------------------------
__global__ __launch_bounds__(256)
void attn_kernel(const float* __restrict__ qkv, float* __restrict__ outp) {
  __shared__ float QsT[64][68];  // [d][r]
  __shared__ float KsT[64][68];  // [d][c]
  __shared__ float Vs[64][68];   // [c][d]
  __shared__ float Ps[64][68];   // [c][r]  (S^T, then P^T)
  __shared__ float mrow[64], lrow[64], arow[64];

  const int tid = threadIdx.x;
  const int bh = blockIdx.y;
  const int b = bh >> 2, h = bh & 3;
  const int q0 = blockIdx.x * 64;
  const int tr = tid >> 4, tc = tid & 15;
  const int row4 = tr * 4, col4 = tc * 4;
  const int lr = tid >> 2;            // token row handled in loads
  const int ld0 = (tid & 3) * 16;     // dim base in loads

  // load Q tile (transposed)
  {
    const float* qbase =
        qkv + (size_t)(b * T_SZ + q0 + lr) * (3 * D_MODEL) + h * HD;
#pragma unroll
    for (int i = 0; i < 16; i += 4) {
      float4 v = *(const float4*)(qbase + ld0 + i);
      QsT[ld0 + i + 0][lr] = v.x; QsT[ld0 + i + 1][lr] = v.y;
      QsT[ld0 + i + 2][lr] = v.z; QsT[ld0 + i + 3][lr] = v.w;
    }
  }
  if (tid < 64) { mrow[tid] = -1e30f; lrow[tid] = 0.f; }

  float O[4][4] = {};
  const int jmax = q0 >> 6;
  for (int jt = 0; jt <= jmax; ++jt) {
    __syncthreads();  // prev PV done; mrow/lrow init visible on first iter
    const int c0 = jt * 64;
    {
      const float* kbase =
          qkv + (size_t)(b * T_SZ + c0 + lr) * (3 * D_MODEL) + D_MODEL + h * HD;
      const float* vbase = kbase + D_MODEL;
#pragma unroll
      for (int i = 0; i < 16; i += 4) {
        float4 kv = *(const float4*)(kbase + ld0 + i);
        KsT[ld0 + i + 0][lr] = kv.x; KsT[ld0 + i + 1][lr] = kv.y;
        KsT[ld0 + i + 2][lr] = kv.z; KsT[ld0 + i + 3][lr] = kv.w;
        float4 vv = *(const float4*)(vbase + ld0 + i);
        *(float4*)&Vs[lr][ld0 + i] = vv;
      }
    }
    __syncthreads();

    // S = Q K^T (64x64), 4x4 per thread
    float s[4][4] = {};
#pragma unroll 8
    for (int d = 0; d < 64; ++d) {
      float4 qa = *(const float4*)&QsT[d][row4];
      float4 ka = *(const float4*)&KsT[d][col4];
      float qq[4] = {qa.x, qa.y, qa.z, qa.w};
      float kk[4] = {ka.x, ka.y, ka.z, ka.w};
#pragma unroll
      for (int i = 0; i < 4; ++i)
#pragma unroll
        for (int j = 0; j < 4; ++j) s[i][j] = fmaf(qq[i], kk[j], s[i][j]);
    }
    // scale + causal mask, write transposed
#pragma unroll
    for (int i = 0; i < 4; ++i)
#pragma unroll
      for (int j = 0; j < 4; ++j) {
        float v = s[i][j] * 0.125f;
        const int gr = q0 + row4 + i, gc = c0 + col4 + j;
        if (gc > gr) v = -1e30f;
        Ps[col4 + j][row4 + i] = v;
      }
    __syncthreads();

    // online softmax, one thread per row
    if (tid < 64) {
      const int r = tid;
      float m_old = mrow[r];
      float mx = m_old;
#pragma unroll 8
      for (int c = 0; c < 64; ++c) mx = fmaxf(mx, Ps[c][r]);
      float alpha = __expf(m_old - mx);
      float sum = 0.f;
#pragma unroll 8
      for (int c = 0; c < 64; ++c) {
        float p = __expf(Ps[c][r] - mx);
        Ps[c][r] = p;
        sum += p;
      }
      mrow[r] = mx;
      lrow[r] = lrow[r] * alpha + sum;
      arow[r] = alpha;
    }
    __syncthreads();

    // O = O*alpha + P V
#pragma unroll
    for (int i = 0; i < 4; ++i) {
      float a = arow[row4 + i];
#pragma unroll
      for (int j = 0; j < 4; ++j) O[i][j] *= a;
    }
#pragma unroll 8
    for (int c = 0; c < 64; ++c) {
      float4 pa = *(const float4*)&Ps[c][row4];
      float4 va = *(const float4*)&Vs[c][col4];
      float pp[4] = {pa.x, pa.y, pa.z, pa.w};
      float vv[4] = {va.x, va.y, va.z, va.w};
#pragma unroll
      for (int i = 0; i < 4; ++i)
#pragma unroll
        for (int j = 0; j < 4; ++j) O[i][j] = fmaf(pp[i], vv[j], O[i][j]);
    }
  }

#pragma unroll
  for (int i = 0; i < 4; ++i) {
    float inv = 1.0f / lrow[row4 + i];
    float* op = outp + (size_t)(b * T_SZ + q0 + row4 + i) * D_MODEL + h * HD + col4;
    float4 o;
    o.x = O[i][0] * inv; o.y = O[i][1] * inv;
    o.z = O[i][2] * inv; o.w = O[i][3] * inv;
    *(float4*)op = o;
  }
}

// ---------------------------------------------------------------------------
// LayerNorm helpers (D=256, one row per 256-thread block)
// ---------------------------------------------------------------------------
__device__ __forceinline__ float block_reduce_sum(float v, float* tmp) {
#pragma unroll
  for (int o = 32; o > 0; o >>= 1) v += __shfl_down(v, o);
  const int lane = threadIdx.x & 63, wid = threadIdx.x >> 6;
  if (lane == 0) tmp[wid] = v;
  __syncthreads();
  v = tmp[0] + tmp[1] + tmp[2] + tmp[3];
  __syncthreads();
  return v;
}

__device__ __forceinline__ float ln_finish(float v, float s1, float s2,
                                           float g, float bb) {
  float mean = s1 * (1.f / 256.f);
  float var = s2 * (1.f / 256.f) - mean * mean;
  return (v - mean) * rsqrtf(var + 1e-5f) * g + bb;
}

__global__ __launch_bounds__(256)
void ln_add_kernel(const float* __restrict__ a, const float* __restrict__ addsrc,
                   const float* __restrict__ g, const float* __restrict__ bb,
                   float* __restrict__ outp) {
  __shared__ float tmp[4];
  const size_t row = blockIdx.x;
  const int d = threadIdx.x;
  float v = a[row * 256 + d] + addsrc[row * 256 + d];
  float s1 = block_reduce_sum(v, tmp);
  float s2 = block_reduce_sum(v * v, tmp);
  outp[row * 256 + d] = ln_finish(v, s1, s2, g[d], bb[d]);
}

// states = LN3( seq_state + 0.5*(local_prefix + chunk_carry) ), in-place on st
__global__ __launch_bounds__(256)
void ln3_states_kernel(float* __restrict__ st, const float* __restrict__ scr,
                       const float* __restrict__ seq, const float* __restrict__ g,
                       const float* __restrict__ bb) {
  __shared__ float tmp[4];
  const int row = blockIdx.x;
  const int b = row >> 10, t = row & 1023;
  const int d = threadIdx.x;
  float v = seq[b * 256 + d] +
            0.5f * (st[(size_t)row * 256 + d] +
                    scr[(size_t)(b * 32 + (t >> 5)) * 256 + d]);
  float s1 = block_reduce_sum(v, tmp);
  float s2 = block_reduce_sum(v * v, tmp);
  st[(size_t)row * 256 + d] = ln_finish(v, s1, s2, g[d], bb[d]);
}

// LN4 on states[:, -1, :] -> out (8 blocks)
__global__ __launch_bounds__(256)
void ln4_kernel(const float* __restrict__ st, const float* __restrict__ g,
                const float* __restrict__ bb, float* __restrict__ outp) {
  __shared__ float tmp[4];
  const int b = blockIdx.x, d = threadIdx.x;
  float v = st[(size_t)(b * T_SZ + 1023) * 256 + d];
  float s1 = block_reduce_sum(v, tmp);
  float s2 = block_reduce_sum(v * v, tmp);
  outp[b * 256 + d] = ln_finish(v, s1, s2, g[d], bb[d]);
}

// ---------------------------------------------------------------------------
// Depthwise causal conv (window 8) -> combined cols [256,512)
// ---------------------------------------------------------------------------
__global__ __launch_bounds__(256)
void conv_kernel(const float* __restrict__ x, const float* __restrict__ w,
                 const float* __restrict__ cb, float* __restrict__ comb) {
  const int row = blockIdx.x;
  const int b = row >> 10, t = row & 1023;
  const int d = threadIdx.x;
  float acc = cb[d];
#pragma unroll
  for (int j = 0; j < 8; ++j) {
    const int ts = t - 7 + j;
    if (ts >= 0)
      acc = fmaf(x[(size_t)(b * T_SZ + ts) * 256 + d], w[d * 8 + j], acc);
  }
  comb[(size_t)row * 768 + 256 + d] = acc;
}

// ---------------------------------------------------------------------------
// EMA (decay 0.9) chunked scan: 32 chunks of 32. Local pass writes combined
// cols [512,768); then chunk-carry scan; then fixup + final summary out.
// ---------------------------------------------------------------------------
__global__ __launch_bounds__(256)
void ema_a_kernel(const float* __restrict__ x, float* __restrict__ comb,
                  float* __restrict__ scr) {
  const int bc = blockIdx.x;
  const int b = bc >> 5, ch = bc & 31;
  const int d = threadIdx.x;
  const int t0 = ch * 32;
  float c = 0.f;
  for (int tl = 0; tl < 32; ++tl) {
    const size_t row = (size_t)(b * T_SZ + t0 + tl);
    c = 0.9f * c + 0.1f * x[row * 256 + d];
    comb[row * 768 + 512 + d] = c;
  }
  scr[(size_t)bc * 256 + d] = c;
}

__global__ __launch_bounds__(256)
void ema_b_kernel(float* __restrict__ scr) {
  const int b = blockIdx.x, d = threadIdx.x;
  const float q32 = 0.03433683820292512f;  // 0.9^32
  float carry = 0.f;
  for (int ch = 0; ch < 32; ++ch) {
    const size_t idx = (size_t)(b * 32 + ch) * 256 + d;
    float e = scr[idx];
    scr[idx] = carry;        // carry-in for this chunk = EMA value before it
    carry = e + q32 * carry;
  }
}

__global__ __launch_bounds__(256)
void ema_c_kernel(float* __restrict__ comb, const float* __restrict__ scr,
                  float* __restrict__ fts) {
  const int row = blockIdx.x;
  const int b = row >> 10, t = row & 1023;
  const int d = threadIdx.x;
  const int ch = t >> 5, tl = t & 31;
  float carry = scr[(size_t)(b * 32 + ch) * 256 + d];
  float l = comb[(size_t)row * 768 + 512 + d];
  float y = fmaf(__powf(0.9f, (float)(tl + 1)), carry, l);
  comb[(size_t)row * 768 + 512 + d] = y;
  if (t == 1023) fts[b * 256 + d] = y;
}

// ---------------------------------------------------------------------------
// cumsum over T, chunked (in-place local prefix on deltas + carry scratch)
// ---------------------------------------------------------------------------
__global__ __launch_bounds__(256)
void cs_a_kernel(float* __restrict__ deltas, float* __restrict__ scr) {
  const int bc = blockIdx.x;
  const int b = bc >> 5, ch = bc & 31;
  const int d = threadIdx.x;
  const int t0 = ch * 32;
  float c = 0.f;
  for (int tl = 0; tl < 32; ++tl) {
    const size_t idx = (size_t)(b * T_SZ + t0 + tl) * 256 + d;
    c += deltas[idx];
    deltas[idx] = c;
  }
  scr[(size_t)bc * 256 + d] = c;
}

__global__ __launch_bounds__(256)
void cs_b_kernel(float* __restrict__ scr) {
  const int b = blockIdx.x, d = threadIdx.x;
  float carry = 0.f;
  for (int ch = 0; ch < 32; ++ch) {
    const size_t idx = (size_t)(b * 32 + ch) * 256 + d;
    float e = scr[idx];
    scr[idx] = carry;
    carry += e;
  }
}

// ---------------------------------------------------------------------------
extern "C" void kernel_launch(void* const* d_in, const int* in_sizes, int n_in,
                              void* d_out, int out_size, void* d_ws,
                              size_t ws_size, hipStream_t stream) {
  (void)in_sizes; (void)n_in; (void)out_size; (void)ws_size;
  const float* parallel_repr = (const float*)d_in[0];
  const float* sequential_state = (const float*)d_in[1];
  const float* in_proj_w = (const float*)d_in[3];
  const float* in_proj_b = (const float*)d_in[4];
  const float* out_proj_w = (const float*)d_in[5];
  const float* out_proj_b = (const float*)d_in[6];
  const float* conv_w = (const float*)d_in[7];
  const float* conv_b = (const float*)d_in[8];
  const float* p2s_w = (const float*)d_in[9];
  const float* p2s_b = (const float*)d_in[10];
  const float* s2p_w = (const float*)d_in[11];
  const float* s2p_b = (const float*)d_in[12];
  const float* trans_w1 = (const float*)d_in[13];
  const float* trans_b1 = (const float*)d_in[14];
  const float* trans_w2 = (const float*)d_in[15];
  const float* trans_b2 = (const float*)d_in[16];
  const float* ffn_w1 = (const float*)d_in[17];
  const float* ffn_b1 = (const float*)d_in[18];
  const float* ffn_w2 = (const float*)d_in[19];
  const float* ffn_b2 = (const float*)d_in[20];
  const float* ln1_s = (const float*)d_in[21];
  const float* ln1_b = (const float*)d_in[22];
  const float* ln2_s = (const float*)d_in[23];
  const float* ln2_b = (const float*)d_in[24];
  const float* ln3_s = (const float*)d_in[25];
  const float* ln3_b = (const float*)d_in[26];
  const float* ln4_s = (const float*)d_in[27];
  const float* ln4_b = (const float*)d_in[28];

  float* ws = (float*)d_ws;
  float* qkv = ws + OFF_R0;   // [8192,768]; later reused as `combined`
  float* comb = qkv;
  float* r1 = ws + OFF_R1;    // attn_out -> deltas -> states
  float* x = ws + OFF_R2;
  float* r3 = ws + OFF_R3;    // attn_raw -> h -> ffn_in -> ffn_out
  float* f = ws;              // [8192,1024] overlays R0+R1 (both dead then)
  float* scr1 = ws + OFF_SCR1;
  float* scr2 = ws + OFF_SCR2;
  float* out = (float*)d_out;
  float* out_fss = out + S_ELT;          // final_sequential_state
  float* out_fts = out + S_ELT + 2048;   // final_trajectory_summary

  const dim3 blk(256);

  // 1. qkv = PR @ in_proj_w^T + b          [8192,768]
  gemm_kernel<EPI_NONE><<<dim3(128, 12), blk, 0, stream>>>(
      parallel_repr, 256, in_proj_w, 256, in_proj_b, qkv, 768, 0, nullptr, 0);
  // 2. attention -> attn_raw (r3)
  attn_kernel<<<dim3(16, 32), blk, 0, stream>>>(qkv, r3);
  // 3. attn_out = attn_raw @ out_proj^T + b -> r1
  gemm_kernel<EPI_NONE><<<dim3(128, 4), blk, 0, stream>>>(
      r3, 256, out_proj_w, 256, out_proj_b, r1, 256, 0, nullptr, 0);
  // 4. x = LN1(PR + attn_out)
  ln_add_kernel<<<8192, blk, 0, stream>>>(parallel_repr, r1, ln1_s, ln1_b, x);
  // 5. depthwise conv -> combined[:,256:512]
  conv_kernel<<<8192, blk, 0, stream>>>(x, conv_w, conv_b, comb);
  // 6-8. EMA -> combined[:,512:768] (+ final traj summary out)
  ema_a_kernel<<<256, blk, 0, stream>>>(x, comb, scr1);
  ema_b_kernel<<<8, blk, 0, stream>>>(scr1);
  ema_c_kernel<<<8192, blk, 0, stream>>>(comb, scr1, out_fts);
  // 9. combined[:,0:256] = x + 0.3*(x @ p2s^T + b)
  gemm_kernel<EPI_ADDSCALE><<<dim3(128, 4), blk, 0, stream>>>(
      x, 256, p2s_w, 256, p2s_b, comb, 768, 0, x, 256);
  // 10. h = gelu(combined @ trans_w1^T + b1) -> r3   [8192,512]
  gemm_kernel<EPI_GELU><<<dim3(128, 8), blk, 0, stream>>>(
      comb, 768, trans_w1, 768, trans_b1, r3, 512, 0, nullptr, 0);
  // 11. deltas = h @ trans_w2^T + b2 -> r1
  gemm_kernel<EPI_NONE><<<dim3(128, 4), blk, 0, stream>>>(
      r3, 512, trans_w2, 512, trans_b2, r1, 256, 0, nullptr, 0);
  // 12-13. chunked cumsum on deltas
  cs_a_kernel<<<256, blk, 0, stream>>>(r1, scr2);
  cs_b_kernel<<<8, blk, 0, stream>>>(scr2);
  // 14. states = LN3(seq + 0.5*cumsum) in-place
  ln3_states_kernel<<<8192, blk, 0, stream>>>(r1, scr2, sequential_state,
                                              ln3_s, ln3_b);
  // 15. final_sequential_state = LN4(states[:, -1])
  ln4_kernel<<<8, blk, 0, stream>>>(r1, ln4_s, ln4_b, out_fss);
  // 16. ffn_in = x + 0.3*(states @ s2p^T + b) -> r3[0:S]
  gemm_kernel<EPI_ADDSCALE><<<dim3(128, 4), blk, 0, stream>>>(
      r1, 256, s2p_w, 256, s2p_b, r3, 256, 0, x, 256);
  // 17. f = gelu(ffn_in @ ffn_w1^T + b1) -> ws[0:4S]   [8192,1024]
  gemm_kernel<EPI_GELU><<<dim3(128, 16), blk, 0, stream>>>(
      r3, 256, ffn_w1, 256, ffn_b1, f, 1024, 0, nullptr, 0);
  // 18. ffn_out = f @ ffn_w2^T + b2 -> r3[0:S]
  gemm_kernel<EPI_NONE><<<dim3(128, 4), blk, 0, stream>>>(
      f, 1024, ffn_w2, 1024, ffn_b2, r3, 256, 0, nullptr, 0);
  // 19. out_x = LN2(x + ffn_out)
  ln_add_kernel<<<8192, blk, 0, stream>>>(x, r3, ln2_s, ln2_b, out);
}

// Round 2
// 395.817 us; speedup vs baseline: 1.9318x; 1.9318x over previous
//
#include <hip/hip_runtime.h>
#include <math.h>

typedef unsigned short u16;
typedef __attribute__((ext_vector_type(8))) short bf16x8;
typedef __attribute__((ext_vector_type(4))) float f32x4;

#define D_MODEL 256
#define T_SZ 1024
constexpr size_t S_ELT = (size_t)8192 * 256;
constexpr size_t MB = 1024 * 1024;

// workspace byte offsets
constexpr size_t OFF_QKV = 0;          // u16 [8192][768] (12MB); later f overlays [0,16MB)
constexpr size_t OFF_ATTN = 12 * MB;   // u16 [8192][256] (4MB); later states_bf
constexpr size_t OFF_F = 0;            // u16 [8192][1024] (16MB)
constexpr size_t OFF_X = 16 * MB;      // f32 [8192][256] (8MB)
constexpr size_t OFF_COMB = 24 * MB;   // u16 [8192][768] (12MB); later ffn_in (4MB)
constexpr size_t OFF_FB = 36 * MB;     // f32 [8192][256]: attn_out -> deltas -> ffn_out
constexpr size_t OFF_H = 44 * MB;      // u16 [8192][512] (8MB)
constexpr size_t OFF_WB = 52 * MB;     // u16 weights (2.75MB)
constexpr size_t OFF_SCR1 = 55 * MB;           // f32 65536
constexpr size_t OFF_SCR2 = 55 * MB + 262144;  // f32 65536

// bf16 weight element offsets inside WB
constexpr int WB_INPROJ = 0;
constexpr int WB_OUTPROJ = 196608;
constexpr int WB_P2S = 262144;
constexpr int WB_S2P = 327680;
constexpr int WB_T1 = 393216;
constexpr int WB_T2 = 786432;
constexpr int WB_F1 = 917504;
constexpr int WB_F2 = 1179648;
constexpr int WB_TOTAL = 1441792;

__device__ __forceinline__ u16 f2bf(float f) {
  unsigned int u = __float_as_uint(f);
  u += 0x7fff + ((u >> 16) & 1);
  return (u16)(u >> 16);
}
__device__ __forceinline__ float bf2f(u16 s) {
  return __uint_as_float(((unsigned int)s) << 16);
}

// ---------------------------------------------------------------------------
// weight fp32 -> bf16 conversion (all 8 matrices, 4 elems/thread)
// ---------------------------------------------------------------------------
__global__ __launch_bounds__(256)
void wconv_kernel(const float* w0, const float* w1, const float* w2,
                  const float* w3, const float* w4, const float* w5,
                  const float* w6, const float* w7, u16* __restrict__ outp) {
  const int idx4 = (blockIdx.x * 256 + threadIdx.x) * 4;
  if (idx4 >= WB_TOTAL) return;
  const int offs[9] = {WB_INPROJ, WB_OUTPROJ, WB_P2S,  WB_S2P, WB_T1,
                       WB_T2,     WB_F1,      WB_F2,   WB_TOTAL};
  const float* srcs[8] = {w0, w1, w2, w3, w4, w5, w6, w7};
  int seg = 0;
  while (idx4 >= offs[seg + 1]) ++seg;
  float4 v = *(const float4*)(srcs[seg] + (idx4 - offs[seg]));
  u16 o0 = f2bf(v.x), o1 = f2bf(v.y), o2 = f2bf(v.z), o3 = f2bf(v.w);
  unsigned int lo = (unsigned int)o0 | ((unsigned int)o1 << 16);
  unsigned int hi = (unsigned int)o2 | ((unsigned int)o3 << 16);
  uint2 pk = make_uint2(lo, hi);
  *(uint2*)(outp + idx4) = pk;
}

// ---------------------------------------------------------------------------
// bf16 MFMA GEMM: C = epi(A @ W^T + bias). W bf16 [N][K] row-major.
// BM=128, BK=32, 4 waves. BN=128: waves 2x2, wave tile 64x64.
//                         BN=64 : waves 4x1, wave tile 32x64.
// ---------------------------------------------------------------------------
enum { EPI_NONE = 0, EPI_GELU = 1, EPI_ADDSCALE = 2 };

template <int EPI, int BN, bool OUTBF, bool AF32>
__global__ __launch_bounds__(256)
void mgemm(const void* __restrict__ Av, int lda,
           const u16* __restrict__ Wb, int K, const float* __restrict__ bias,
           void* __restrict__ Cv, int ldc, int col_off,
           const float* __restrict__ addsrc) {
  __shared__ u16 As[128][40];
  __shared__ u16 Bs[BN][40];
  const int tid = threadIdx.x;
  const int m0 = blockIdx.x * 128;
  const int n0 = blockIdx.y * BN;
  const int w = tid >> 6, lane = tid & 63;
  const int ln = lane & 15, quad = lane >> 4, kq8 = quad * 8;
  constexpr int MT = (BN == 128) ? 4 : 2;
  const int wm = (BN == 128) ? (w >> 1) * 64 : w * 32;
  const int wn = (BN == 128) ? (w & 1) * 64 : 0;

  f32x4 acc[MT][4] = {};

  const int srow = tid >> 2, skq = tid & 3;

  for (int k0 = 0; k0 < K; k0 += 32) {
    // --- stage A (128x32 bf16) ---
    if (AF32) {
      const float* Af = (const float*)Av;
#pragma unroll
      for (int p = 0; p < 2; ++p) {
        const int row = srow + p * 64;
        const float* ap = Af + (size_t)(m0 + row) * lda + k0 + skq * 8;
        float4 v0 = *(const float4*)ap;
        float4 v1 = *(const float4*)(ap + 4);
        union { u16 h[8]; uint4 u; } pk;
        pk.h[0] = f2bf(v0.x); pk.h[1] = f2bf(v0.y);
        pk.h[2] = f2bf(v0.z); pk.h[3] = f2bf(v0.w);
        pk.h[4] = f2bf(v1.x); pk.h[5] = f2bf(v1.y);
        pk.h[6] = f2bf(v1.z); pk.h[7] = f2bf(v1.w);
        *(uint4*)&As[row][skq * 8] = pk.u;
      }
    } else {
      const u16* Ab = (const u16*)Av;
#pragma unroll
      for (int p = 0; p < 2; ++p) {
        const int row = srow + p * 64;
        *(uint4*)&As[row][skq * 8] =
            *(const uint4*)(Ab + (size_t)(m0 + row) * lda + k0 + skq * 8);
      }
    }
    // --- stage B (BNx32 bf16) ---
    *(uint4*)&Bs[srow][skq * 8] =
        *(const uint4*)(Wb + (size_t)(n0 + srow) * K + k0 + skq * 8);
    if (BN == 128) {
      *(uint4*)&Bs[srow + 64][skq * 8] =
          *(const uint4*)(Wb + (size_t)(n0 + srow + 64) * K + k0 + skq * 8);
    }
    __syncthreads();

    bf16x8 af[MT], bv[4];
#pragma unroll
    for (int i = 0; i < MT; ++i)
      af[i] = *(const bf16x8*)&As[wm + i * 16 + ln][kq8];
#pragma unroll
    for (int j = 0; j < 4; ++j)
      bv[j] = *(const bf16x8*)&Bs[wn + j * 16 + ln][kq8];
#pragma unroll
    for (int i = 0; i < MT; ++i)
#pragma unroll
      for (int j = 0; j < 4; ++j)
        acc[i][j] =
            __builtin_amdgcn_mfma_f32_16x16x32_bf16(af[i], bv[j], acc[i][j], 0, 0, 0);
    __syncthreads();
  }

  // --- epilogue ---
#pragma unroll
  for (int i = 0; i < MT; ++i)
#pragma unroll
    for (int j = 0; j < 4; ++j) {
      const int col = n0 + wn + j * 16 + ln;
      const float bsv = bias[col];
#pragma unroll
      for (int r = 0; r < 4; ++r) {
        const int row = m0 + wm + i * 16 + quad * 4 + r;
        float v = acc[i][j][r] + bsv;
        if (EPI == EPI_GELU) v = 0.5f * v * (1.0f + erff(v * 0.70710678f));
        if (EPI == EPI_ADDSCALE) v = addsrc[(size_t)row * 256 + col] + 0.3f * v;
        if (OUTBF)
          ((u16*)Cv)[(size_t)row * ldc + col_off + col] = f2bf(v);
        else
          ((float*)Cv)[(size_t)row * ldc + col_off + col] = v;
      }
    }
}

// ---------------------------------------------------------------------------
// MFMA flash attention: block = 128 q rows x (b,h). 4 waves, 32 q rows each.
// qkv bf16 [8192][768]; out bf16 [8192][256]. causal, scale 1/8.
// ---------------------------------------------------------------------------
__global__ __launch_bounds__(256)
void attn_mfma(const u16* __restrict__ qkv, u16* __restrict__ outp) {
  __shared__ u16 VsT[64][72];     // [d][c]
  __shared__ u16 Ps[4][32][72];   // per-wave P tile [m][c]
  const int tid = threadIdx.x;
  const int w = tid >> 6, lane = tid & 63;
  const int ln = lane & 15, quad = lane >> 4, kq8 = quad * 8;
  const int q0 = blockIdx.x * 128;
  const int bh = blockIdx.y;
  const int b = bh >> 2, h = bh & 3;
  const int wm = w * 32;
  const u16* base = qkv + (size_t)b * T_SZ * 768;

  // Q fragments (A-operand), held in regs for the whole block
  bf16x8 qf[2][2];
#pragma unroll
  for (int i = 0; i < 2; ++i)
#pragma unroll
    for (int ks = 0; ks < 2; ++ks)
      qf[i][ks] = *(const bf16x8*)(base + (size_t)(q0 + wm + i * 16 + ln) * 768 +
                                   h * 64 + ks * 32 + kq8);

  f32x4 O[2][4] = {};
  float mrow[2][4], lrow[2][4];
#pragma unroll
  for (int i = 0; i < 2; ++i)
#pragma unroll
    for (int r = 0; r < 4; ++r) { mrow[i][r] = -1e30f; lrow[i][r] = 0.f; }

  const int ntiles = (q0 >> 6) + 2;
  for (int jt = 0; jt < ntiles; ++jt) {
    const int c0 = jt * 64;
    // stage V transposed
    {
      const int c = tid >> 2, d0 = (tid & 3) * 16;
      const u16* vp = base + (size_t)(c0 + c) * 768 + 512 + h * 64 + d0;
      union { u16 h16[8]; uint4 u; } a0, a1;
      a0.u = *(const uint4*)vp;
      a1.u = *(const uint4*)(vp + 8);
#pragma unroll
      for (int e = 0; e < 8; ++e) VsT[d0 + e][c] = a0.h16[e];
#pragma unroll
      for (int e = 0; e < 8; ++e) VsT[d0 + 8 + e][c] = a1.h16[e];
    }
    __syncthreads();
    const bool active = (c0 <= q0 + wm + 31);
    if (active) {
      // S = Q K^T, K fragments straight from global
      f32x4 s[2][4] = {};
#pragma unroll
      for (int ks = 0; ks < 2; ++ks)
#pragma unroll
        for (int j = 0; j < 4; ++j) {
          bf16x8 kf = *(const bf16x8*)(base + (size_t)(c0 + j * 16 + ln) * 768 +
                                       256 + h * 64 + ks * 32 + kq8);
#pragma unroll
          for (int i = 0; i < 2; ++i)
            s[i][j] = __builtin_amdgcn_mfma_f32_16x16x32_bf16(qf[i][ks], kf,
                                                              s[i][j], 0, 0, 0);
        }
      const bool need_mask = (c0 + 63 > q0 + wm);
#pragma unroll
      for (int i = 0; i < 2; ++i)
#pragma unroll
        for (int j = 0; j < 4; ++j)
#pragma unroll
          for (int r = 0; r < 4; ++r) {
            float v = s[i][j][r] * 0.125f;
            if (need_mask) {
              const int row = q0 + wm + i * 16 + quad * 4 + r;
              const int col = c0 + j * 16 + ln;
              if (col > row) v = -1e30f;
            }
            s[i][j][r] = v;
          }
      // online softmax, all in regs + shfl over the 16-lane col groups
#pragma unroll
      for (int i = 0; i < 2; ++i)
#pragma unroll
        for (int r = 0; r < 4; ++r) {
          float tmx = fmaxf(fmaxf(s[i][0][r], s[i][1][r]),
                            fmaxf(s[i][2][r], s[i][3][r]));
#pragma unroll
          for (int m = 1; m <= 8; m <<= 1) tmx = fmaxf(tmx, __shfl_xor(tmx, m, 64));
          const float mold = mrow[i][r];
          const float mnew = fmaxf(mold, tmx);
          const float alpha = __expf(mold - mnew);
          float psum = 0.f;
#pragma unroll
          for (int j = 0; j < 4; ++j) {
            float p = __expf(s[i][j][r] - mnew);
            s[i][j][r] = p;
            psum += p;
          }
#pragma unroll
          for (int m = 1; m <= 8; m <<= 1) psum += __shfl_xor(psum, m, 64);
          mrow[i][r] = mnew;
          lrow[i][r] = lrow[i][r] * alpha + psum;
#pragma unroll
          for (int j = 0; j < 4; ++j) O[i][j][r] *= alpha;
#pragma unroll
          for (int j = 0; j < 4; ++j)
            Ps[w][i * 16 + quad * 4 + r][j * 16 + ln] = f2bf(s[i][j][r]);
        }
      // O += P V
#pragma unroll
      for (int ks = 0; ks < 2; ++ks) {
        bf16x8 pf0 = *(const bf16x8*)&Ps[w][ln][ks * 32 + kq8];
        bf16x8 pf1 = *(const bf16x8*)&Ps[w][16 + ln][ks * 32 + kq8];
#pragma unroll
        for (int j = 0; j < 4; ++j) {
          bf16x8 vf = *(const bf16x8*)&VsT[j * 16 + ln][ks * 32 + kq8];
          O[0][j] = __builtin_amdgcn_mfma_f32_16x16x32_bf16(pf0, vf, O[0][j], 0, 0, 0);
          O[1][j] = __builtin_amdgcn_mfma_f32_16x16x32_bf16(pf1, vf, O[1][j], 0, 0, 0);
        }
      }
    }
    __syncthreads();
  }
  u16* op = outp + (size_t)b * T_SZ * 256;
#pragma unroll
  for (int i = 0; i < 2; ++i)
#pragma unroll
    for (int r = 0; r < 4; ++r) {
      const float inv = 1.f / lrow[i][r];
#pragma unroll
      for (int j = 0; j < 4; ++j)
        op[(size_t)(q0 + wm + i * 16 + quad * 4 + r) * 256 + h * 64 + j * 16 + ln] =
            f2bf(O[i][j][r] * inv);
    }
}

// ---------------------------------------------------------------------------
// LayerNorm + misc elementwise (fp32 math)
// ---------------------------------------------------------------------------
__device__ __forceinline__ float block_reduce_sum(float v, float* tmp) {
#pragma unroll
  for (int o = 32; o > 0; o >>= 1) v += __shfl_down(v, o);
  const int lane = threadIdx.x & 63, wid = threadIdx.x >> 6;
  if (lane == 0) tmp[wid] = v;
  __syncthreads();
  v = tmp[0] + tmp[1] + tmp[2] + tmp[3];
  __syncthreads();
  return v;
}

__device__ __forceinline__ float ln_finish(float v, float s1, float s2,
                                           float g, float bb) {
  float mean = s1 * (1.f / 256.f);
  float var = s2 * (1.f / 256.f) - mean * mean;
  return (v - mean) * rsqrtf(var + 1e-5f) * g + bb;
}

__global__ __launch_bounds__(256)
void ln_add_kernel(const float* __restrict__ a, const float* __restrict__ addsrc,
                   const float* __restrict__ g, const float* __restrict__ bb,
                   float* __restrict__ outp) {
  __shared__ float tmp[4];
  const size_t row = blockIdx.x;
  const int d = threadIdx.x;
  float v = a[row * 256 + d] + addsrc[row * 256 + d];
  float s1 = block_reduce_sum(v, tmp);
  float s2 = block_reduce_sum(v * v, tmp);
  outp[row * 256 + d] = ln_finish(v, s1, s2, g[d], bb[d]);
}

// states = LN3(seq + 0.5*(local_cumsum + carry)) -> bf16
__global__ __launch_bounds__(256)
void ln3_states_kernel(const float* __restrict__ deltas, const float* __restrict__ scr,
                       const float* __restrict__ seq, const float* __restrict__ g,
                       const float* __restrict__ bb, u16* __restrict__ st) {
  __shared__ float tmp[4];
  const int row = blockIdx.x;
  const int b = row >> 10, t = row & 1023;
  const int d = threadIdx.x;
  float v = seq[b * 256 + d] +
            0.5f * (deltas[(size_t)row * 256 + d] +
                    scr[(size_t)(b * 32 + (t >> 5)) * 256 + d]);
  float s1 = block_reduce_sum(v, tmp);
  float s2 = block_reduce_sum(v * v, tmp);
  st[(size_t)row * 256 + d] = f2bf(ln_finish(v, s1, s2, g[d], bb[d]));
}

__global__ __launch_bounds__(256)
void ln4_kernel(const u16* __restrict__ st, const float* __restrict__ g,
                const float* __restrict__ bb, float* __restrict__ outp) {
  __shared__ float tmp[4];
  const int b = blockIdx.x, d = threadIdx.x;
  float v = bf2f(st[(size_t)(b * T_SZ + 1023) * 256 + d]);
  float s1 = block_reduce_sum(v, tmp);
  float s2 = block_reduce_sum(v * v, tmp);
  outp[b * 256 + d] = ln_finish(v, s1, s2, g[d], bb[d]);
}

__global__ __launch_bounds__(256)
void conv_kernel(const float* __restrict__ x, const float* __restrict__ w,
                 const float* __restrict__ cb, u16* __restrict__ comb) {
  const int row = blockIdx.x;
  const int b = row >> 10, t = row & 1023;
  const int d = threadIdx.x;
  float acc = cb[d];
#pragma unroll
  for (int j = 0; j < 8; ++j) {
    const int ts = t - 7 + j;
    if (ts >= 0)
      acc = fmaf(x[(size_t)(b * T_SZ + ts) * 256 + d], w[d * 8 + j], acc);
  }
  comb[(size_t)row * 768 + 256 + d] = f2bf(acc);
}

__global__ __launch_bounds__(256)
void ema_a_kernel(const float* __restrict__ x, u16* __restrict__ comb,
                  float* __restrict__ scr) {
  const int bc = blockIdx.x;
  const int b = bc >> 5, ch = bc & 31;
  const int d = threadIdx.x;
  const int t0 = ch * 32;
  float c = 0.f;
  for (int tl = 0; tl < 32; ++tl) {
    const size_t row = (size_t)(b * T_SZ + t0 + tl);
    c = 0.9f * c + 0.1f * x[row * 256 + d];
    comb[row * 768 + 512 + d] = f2bf(c);
  }
  scr[(size_t)bc * 256 + d] = c;
}

__global__ __launch_bounds__(256)
void ema_b_kernel(float* __restrict__ scr) {
  const int b = blockIdx.x, d = threadIdx.x;
  const float q32 = 0.03433683820292512f;  // 0.9^32
  float carry = 0.f;
  for (int ch = 0; ch < 32; ++ch) {
    const size_t idx = (size_t)(b * 32 + ch) * 256 + d;
    float e = scr[idx];
    scr[idx] = carry;
    carry = e + q32 * carry;
  }
}

__global__ __launch_bounds__(256)
void ema_c_kernel(u16* __restrict__ comb, const float* __restrict__ scr,
                  float* __restrict__ fts) {
  const int row = blockIdx.x;
  const int b = row >> 10, t = row & 1023;
  const int d = threadIdx.x;
  const int ch = t >> 5, tl = t & 31;
  float carry = scr[(size_t)(b * 32 + ch) * 256 + d];
  float l = bf2f(comb[(size_t)row * 768 + 512 + d]);
  float y = fmaf(__powf(0.9f, (float)(tl + 1)), carry, l);
  comb[(size_t)row * 768 + 512 + d] = f2bf(y);
  if (t == 1023) fts[b * 256 + d] = y;
}

__global__ __launch_bounds__(256)
void cs_a_kernel(float* __restrict__ deltas, float* __restrict__ scr) {
  const int bc = blockIdx.x;
  const int b = bc >> 5, ch = bc & 31;
  const int d = threadIdx.x;
  const int t0 = ch * 32;
  float c = 0.f;
  for (int tl = 0; tl < 32; ++tl) {
    const size_t idx = (size_t)(b * T_SZ + t0 + tl) * 256 + d;
    c += deltas[idx];
    deltas[idx] = c;
  }
  scr[(size_t)bc * 256 + d] = c;
}

__global__ __launch_bounds__(256)
void cs_b_kernel(float* __restrict__ scr) {
  const int b = blockIdx.x, d = threadIdx.x;
  float carry = 0.f;
  for (int ch = 0; ch < 32; ++ch) {
    const size_t idx = (size_t)(b * 32 + ch) * 256 + d;
    float e = scr[idx];
    scr[idx] = carry;
    carry += e;
  }
}

// ---------------------------------------------------------------------------
extern "C" void kernel_launch(void* const* d_in, const int* in_sizes, int n_in,
                              void* d_out, int out_size, void* d_ws,
                              size_t ws_size, hipStream_t stream) {
  (void)in_sizes; (void)n_in; (void)out_size; (void)ws_size;
  const float* parallel_repr = (const float*)d_in[0];
  const float* sequential_state = (const float*)d_in[1];
  const float* in_proj_w = (const float*)d_in[3];
  const float* in_proj_b = (const float*)d_in[4];
  const float* out_proj_w = (const float*)d_in[5];
  const float* out_proj_b = (const float*)d_in[6];
  const float* conv_w = (const float*)d_in[7];
  const float* conv_b = (const float*)d_in[8];
  const float* p2s_w = (const float*)d_in[9];
  const float* p2s_b = (const float*)d_in[10];
  const float* s2p_w = (const float*)d_in[11];
  const float* s2p_b = (const float*)d_in[12];
  const float* trans_w1 = (const float*)d_in[13];
  const float* trans_b1 = (const float*)d_in[14];
  const float* trans_w2 = (const float*)d_in[15];
  const float* trans_b2 = (const float*)d_in[16];
  const float* ffn_w1 = (const float*)d_in[17];
  const float* ffn_b1 = (const float*)d_in[18];
  const float* ffn_w2 = (const float*)d_in[19];
  const float* ffn_b2 = (const float*)d_in[20];
  const float* ln1_s = (const float*)d_in[21];
  const float* ln1_b = (const float*)d_in[22];
  const float* ln2_s = (const float*)d_in[23];
  const float* ln2_b = (const float*)d_in[24];
  const float* ln3_s = (const float*)d_in[25];
  const float* ln3_b = (const float*)d_in[26];
  const float* ln4_s = (const float*)d_in[27];
  const float* ln4_b = (const float*)d_in[28];

  char* ws = (char*)d_ws;
  u16* qkv_bf = (u16*)(ws + OFF_QKV);
  u16* attn_bf = (u16*)(ws + OFF_ATTN);
  u16* states_bf = (u16*)(ws + OFF_ATTN);
  u16* f_bf = (u16*)(ws + OFF_F);
  float* x = (float*)(ws + OFF_X);
  u16* comb = (u16*)(ws + OFF_COMB);
  u16* ffn_in = (u16*)(ws + OFF_COMB);
  float* fbuf = (float*)(ws + OFF_FB);
  u16* h_bf = (u16*)(ws + OFF_H);
  u16* wb = (u16*)(ws + OFF_WB);
  float* scr1 = (float*)(ws + OFF_SCR1);
  float* scr2 = (float*)(ws + OFF_SCR2);
  float* out = (float*)d_out;
  float* out_fss = out + S_ELT;
  float* out_fts = out + S_ELT + 2048;

  const dim3 blk(256);

  // 0. weights -> bf16
  wconv_kernel<<<1408, blk, 0, stream>>>(in_proj_w, out_proj_w, p2s_w, s2p_w,
                                         trans_w1, trans_w2, ffn_w1, ffn_w2, wb);
  // 1. qkv = PR @ in_proj^T + b   (A fp32 staged->bf16)
  mgemm<EPI_NONE, 128, true, true><<<dim3(64, 6), blk, 0, stream>>>(
      parallel_repr, 256, wb + WB_INPROJ, 256, in_proj_b, qkv_bf, 768, 0, nullptr);
  // 2. attention
  attn_mfma<<<dim3(8, 32), blk, 0, stream>>>(qkv_bf, attn_bf);
  // 3. attn_out = attn @ out_proj^T + b -> fbuf (fp32)
  mgemm<EPI_NONE, 64, false, false><<<dim3(64, 4), blk, 0, stream>>>(
      attn_bf, 256, wb + WB_OUTPROJ, 256, out_proj_b, fbuf, 256, 0, nullptr);
  // 4. x = LN1(PR + attn_out)
  ln_add_kernel<<<8192, blk, 0, stream>>>(parallel_repr, fbuf, ln1_s, ln1_b, x);
  // 5. conv -> comb[:,256:512]
  conv_kernel<<<8192, blk, 0, stream>>>(x, conv_w, conv_b, comb);
  // 6-8. EMA -> comb[:,512:768] + traj summary
  ema_a_kernel<<<256, blk, 0, stream>>>(x, comb, scr1);
  ema_b_kernel<<<8, blk, 0, stream>>>(scr1);
  ema_c_kernel<<<8192, blk, 0, stream>>>(comb, scr1, out_fts);
  // 9. comb[:,0:256] = x + 0.3*(x @ p2s^T + b)
  mgemm<EPI_ADDSCALE, 64, true, true><<<dim3(64, 4), blk, 0, stream>>>(
      x, 256, wb + WB_P2S, 256, p2s_b, comb, 768, 0, x);
  // 10. h = gelu(comb @ t1^T + b1)
  mgemm<EPI_GELU, 128, true, false><<<dim3(64, 4), blk, 0, stream>>>(
      comb, 768, wb + WB_T1, 768, trans_b1, h_bf, 512, 0, nullptr);
  // 11. deltas = h @ t2^T + b2 -> fbuf (fp32)
  mgemm<EPI_NONE, 64, false, false><<<dim3(64, 4), blk, 0, stream>>>(
      h_bf, 512, wb + WB_T2, 512, trans_b2, fbuf, 256, 0, nullptr);
  // 12-13. cumsum
  cs_a_kernel<<<256, blk, 0, stream>>>(fbuf, scr2);
  cs_b_kernel<<<8, blk, 0, stream>>>(scr2);
  // 14. states = LN3(...) -> bf16
  ln3_states_kernel<<<8192, blk, 0, stream>>>(fbuf, scr2, sequential_state,
                                              ln3_s, ln3_b, states_bf);
  // 15. fss = LN4(states[:,-1])
  ln4_kernel<<<8, blk, 0, stream>>>(states_bf, ln4_s, ln4_b, out_fss);
  // 16. ffn_in = x + 0.3*(states @ s2p^T + b)
  mgemm<EPI_ADDSCALE, 64, true, false><<<dim3(64, 4), blk, 0, stream>>>(
      states_bf, 256, wb + WB_S2P, 256, s2p_b, ffn_in, 256, 0, x);
  // 17. f = gelu(ffn_in @ ffn1^T + b1)
  mgemm<EPI_GELU, 128, true, false><<<dim3(64, 8), blk, 0, stream>>>(
      ffn_in, 256, wb + WB_F1, 256, ffn_b1, f_bf, 1024, 0, nullptr);
  // 18. ffn_out = f @ ffn2^T + b2 -> fbuf
  mgemm<EPI_NONE, 64, false, false><<<dim3(64, 4), blk, 0, stream>>>(
      f_bf, 1024, wb + WB_F2, 1024, ffn_b2, fbuf, 256, 0, nullptr);
  // 19. out = LN2(x + ffn_out)
  ln_add_kernel<<<8192, blk, 0, stream>>>(x, fbuf, ln2_s, ln2_b, out);
}

// Round 3
// 316.426 us; speedup vs baseline: 2.4165x; 1.2509x over previous
//
#include <hip/hip_runtime.h>
#include <math.h>

typedef unsigned short u16;
typedef __attribute__((ext_vector_type(8))) short bf16x8;
typedef __attribute__((ext_vector_type(4))) float f32x4;

#define D_MODEL 256
#define T_SZ 1024
constexpr size_t S_ELT = (size_t)8192 * 256;
constexpr size_t MB = 1024 * 1024;

// workspace byte offsets
constexpr size_t OFF_QKV = 0;          // u16 [8192][768] (12MB); later f overlays [0,16MB)
constexpr size_t OFF_ATTN = 12 * MB;   // u16 [8192][256] (4MB); later states_bf
constexpr size_t OFF_F = 0;            // u16 [8192][1024] (16MB)
constexpr size_t OFF_X = 16 * MB;      // f32 [8192][256] (8MB)
constexpr size_t OFF_COMB = 24 * MB;   // u16 [8192][768] (12MB); later ffn_in (4MB)
constexpr size_t OFF_FB = 36 * MB;     // f32 [8192][256]: attn_out -> deltas -> ffn_out
constexpr size_t OFF_H = 44 * MB;      // u16: vt (4MB, dead after attn) then h (8MB)
constexpr size_t OFF_WB = 52 * MB;     // u16 weights (2.75MB)
constexpr size_t OFF_SCR1 = 55 * MB;           // f32 65536
constexpr size_t OFF_SCR2 = 55 * MB + 262144;  // f32 65536

// bf16 weight element offsets inside WB
constexpr int WB_INPROJ = 0;
constexpr int WB_OUTPROJ = 196608;
constexpr int WB_P2S = 262144;
constexpr int WB_S2P = 327680;
constexpr int WB_T1 = 393216;
constexpr int WB_T2 = 786432;
constexpr int WB_F1 = 917504;
constexpr int WB_F2 = 1179648;
constexpr int WB_TOTAL = 1441792;

__device__ __forceinline__ u16 f2bf(float f) {
  unsigned int u = __float_as_uint(f);
  u += 0x7fff + ((u >> 16) & 1);
  return (u16)(u >> 16);
}
__device__ __forceinline__ float bf2f(u16 s) {
  return __uint_as_float(((unsigned int)s) << 16);
}

// ---------------------------------------------------------------------------
// weight fp32 -> bf16 conversion
// ---------------------------------------------------------------------------
__global__ __launch_bounds__(256)
void wconv_kernel(const float* w0, const float* w1, const float* w2,
                  const float* w3, const float* w4, const float* w5,
                  const float* w6, const float* w7, u16* __restrict__ outp) {
  const int idx4 = (blockIdx.x * 256 + threadIdx.x) * 4;
  if (idx4 >= WB_TOTAL) return;
  const int offs[9] = {WB_INPROJ, WB_OUTPROJ, WB_P2S,  WB_S2P, WB_T1,
                       WB_T2,     WB_F1,      WB_F2,   WB_TOTAL};
  const float* srcs[8] = {w0, w1, w2, w3, w4, w5, w6, w7};
  int seg = 0;
  while (idx4 >= offs[seg + 1]) ++seg;
  float4 v = *(const float4*)(srcs[seg] + (idx4 - offs[seg]));
  u16 o0 = f2bf(v.x), o1 = f2bf(v.y), o2 = f2bf(v.z), o3 = f2bf(v.w);
  unsigned int lo = (unsigned int)o0 | ((unsigned int)o1 << 16);
  unsigned int hi = (unsigned int)o2 | ((unsigned int)o3 << 16);
  uint2 pk = make_uint2(lo, hi);
  *(uint2*)(outp + idx4) = pk;
}

// ---------------------------------------------------------------------------
// bf16 MFMA GEMM: C = epi(A @ W^T + bias). W bf16 [N][K] row-major.
// BM=128, BK=32, 4 waves. BN=128: waves 2x2 (64x64); BN=64: 4x1 (32x64).
// ---------------------------------------------------------------------------
enum { EPI_NONE = 0, EPI_GELU = 1, EPI_ADDSCALE = 2 };

template <int EPI, int BN, bool OUTBF, bool AF32>
__global__ __launch_bounds__(256)
void mgemm(const void* __restrict__ Av, int lda,
           const u16* __restrict__ Wb, int K, const float* __restrict__ bias,
           void* __restrict__ Cv, int ldc, int col_off,
           const float* __restrict__ addsrc) {
  __shared__ u16 As[128][40];
  __shared__ u16 Bs[BN][40];
  const int tid = threadIdx.x;
  const int m0 = blockIdx.x * 128;
  const int n0 = blockIdx.y * BN;
  const int w = tid >> 6, lane = tid & 63;
  const int ln = lane & 15, quad = lane >> 4, kq8 = quad * 8;
  constexpr int MT = (BN == 128) ? 4 : 2;
  const int wm = (BN == 128) ? (w >> 1) * 64 : w * 32;
  const int wn = (BN == 128) ? (w & 1) * 64 : 0;

  f32x4 acc[MT][4] = {};

  const int srow = tid >> 2, skq = tid & 3;

  for (int k0 = 0; k0 < K; k0 += 32) {
    if (AF32) {
      const float* Af = (const float*)Av;
#pragma unroll
      for (int p = 0; p < 2; ++p) {
        const int row = srow + p * 64;
        const float* ap = Af + (size_t)(m0 + row) * lda + k0 + skq * 8;
        float4 v0 = *(const float4*)ap;
        float4 v1 = *(const float4*)(ap + 4);
        union { u16 h[8]; uint4 u; } pk;
        pk.h[0] = f2bf(v0.x); pk.h[1] = f2bf(v0.y);
        pk.h[2] = f2bf(v0.z); pk.h[3] = f2bf(v0.w);
        pk.h[4] = f2bf(v1.x); pk.h[5] = f2bf(v1.y);
        pk.h[6] = f2bf(v1.z); pk.h[7] = f2bf(v1.w);
        *(uint4*)&As[row][skq * 8] = pk.u;
      }
    } else {
      const u16* Ab = (const u16*)Av;
#pragma unroll
      for (int p = 0; p < 2; ++p) {
        const int row = srow + p * 64;
        *(uint4*)&As[row][skq * 8] =
            *(const uint4*)(Ab + (size_t)(m0 + row) * lda + k0 + skq * 8);
      }
    }
    *(uint4*)&Bs[srow][skq * 8] =
        *(const uint4*)(Wb + (size_t)(n0 + srow) * K + k0 + skq * 8);
    if (BN == 128) {
      *(uint4*)&Bs[srow + 64][skq * 8] =
          *(const uint4*)(Wb + (size_t)(n0 + srow + 64) * K + k0 + skq * 8);
    }
    __syncthreads();

    bf16x8 af[MT], bv[4];
#pragma unroll
    for (int i = 0; i < MT; ++i)
      af[i] = *(const bf16x8*)&As[wm + i * 16 + ln][kq8];
#pragma unroll
    for (int j = 0; j < 4; ++j)
      bv[j] = *(const bf16x8*)&Bs[wn + j * 16 + ln][kq8];
#pragma unroll
    for (int i = 0; i < MT; ++i)
#pragma unroll
      for (int j = 0; j < 4; ++j)
        acc[i][j] =
            __builtin_amdgcn_mfma_f32_16x16x32_bf16(af[i], bv[j], acc[i][j], 0, 0, 0);
    __syncthreads();
  }

#pragma unroll
  for (int i = 0; i < MT; ++i)
#pragma unroll
    for (int j = 0; j < 4; ++j) {
      const int col = n0 + wn + j * 16 + ln;
      const float bsv = bias[col];
#pragma unroll
      for (int r = 0; r < 4; ++r) {
        const int row = m0 + wm + i * 16 + quad * 4 + r;
        float v = acc[i][j][r] + bsv;
        if (EPI == EPI_GELU) v = 0.5f * v * (1.0f + erff(v * 0.70710678f));
        if (EPI == EPI_ADDSCALE) v = addsrc[(size_t)row * 256 + col] + 0.3f * v;
        if (OUTBF)
          ((u16*)Cv)[(size_t)row * ldc + col_off + col] = f2bf(v);
        else
          ((float*)Cv)[(size_t)row * ldc + col_off + col] = v;
      }
    }
}

// ---------------------------------------------------------------------------
// V transpose: qkv[b][t][512 + h*64 + d] -> vt[(b*4+h)*64 + d][t]
// ---------------------------------------------------------------------------
__global__ __launch_bounds__(256)
void vtr_kernel(const u16* __restrict__ qkv, u16* __restrict__ vt) {
  __shared__ u16 Ls[64][66];
  const int tid = threadIdx.x;
  const int t0 = blockIdx.x * 64;
  const int bh = blockIdx.y;
  const int b = bh >> 2, h = bh & 3;
  const int r0 = tid >> 3, c8 = (tid & 7) * 8;
#pragma unroll
  for (int p = 0; p < 2; ++p) {
    const int t = t0 + r0 + p * 32;
    *(uint4*)&Ls[r0 + p * 32][c8] =
        *(const uint4*)(qkv + (size_t)(b * T_SZ + t) * 768 + 512 + h * 64 + c8);
  }
  __syncthreads();
#pragma unroll
  for (int p = 0; p < 2; ++p) {
    const int d = r0 + p * 32;
    union { u16 h16[8]; uint4 u; } pk;
#pragma unroll
    for (int e = 0; e < 8; ++e) pk.h16[e] = Ls[c8 + e][d];
    *(uint4*)(vt + (size_t)(bh * 64 + d) * T_SZ + t0 + c8) = pk.u;
  }
}

// ---------------------------------------------------------------------------
// Barrier-free MFMA flash attention. One wave = 16 q rows of one (b,h).
// 2048 wave-units, paired causal load balance. No max-subtraction (scores
// are O(1) for this model); softmax denom accumulated via ones-MFMA.
// ---------------------------------------------------------------------------
__global__ __launch_bounds__(256)
void attn_flash(const u16* __restrict__ qkv, const u16* __restrict__ vt,
                u16* __restrict__ outp) {
  __shared__ u16 Ps[4][16][72];
  const int tid = threadIdx.x;
  const int w = tid >> 6, lane = tid & 63;
  const int ln = lane & 15, quad = lane >> 4, kq8 = quad * 8;
  const int wu = blockIdx.x * 4 + w;
  const int bh = wu >> 6, s = wu & 63;
  const int qt = (s & 1) ? (63 - (s >> 1)) : (s >> 1);
  const int q0 = qt * 16;
  const int b = bh >> 2, h = bh & 3;
  const u16* base = qkv + (size_t)b * T_SZ * 768;
  const u16* vbase = vt + (size_t)bh * 64 * T_SZ;

  bf16x8 qf[2];
#pragma unroll
  for (int ks = 0; ks < 2; ++ks)
    qf[ks] = *(const bf16x8*)(base + (size_t)(q0 + ln) * 768 + h * 64 +
                              ks * 32 + kq8);
  const short ob = (short)0x3F80;
  const bf16x8 ones = {ob, ob, ob, ob, ob, ob, ob, ob};

  f32x4 O[4] = {};
  f32x4 l_acc = {};
  const int ntiles = (qt >> 2) + 1;
  for (int jt = 0; jt < ntiles; ++jt) {
    const int c0 = jt * 64;
    f32x4 sv[4] = {};
#pragma unroll
    for (int ks = 0; ks < 2; ++ks)
#pragma unroll
      for (int j = 0; j < 4; ++j) {
        bf16x8 kf = *(const bf16x8*)(base + (size_t)(c0 + j * 16 + ln) * 768 +
                                     256 + h * 64 + ks * 32 + kq8);
        sv[j] = __builtin_amdgcn_mfma_f32_16x16x32_bf16(qf[ks], kf, sv[j], 0, 0, 0);
      }
    const bool need_mask = (c0 + 63 > q0);
#pragma unroll
    for (int j = 0; j < 4; ++j)
#pragma unroll
      for (int r = 0; r < 4; ++r) {
        float p = __expf(sv[j][r] * 0.125f);
        if (need_mask && (c0 + j * 16 + ln > q0 + quad * 4 + r)) p = 0.f;
        Ps[w][quad * 4 + r][j * 16 + ln] = f2bf(p);
      }
#pragma unroll
    for (int ks = 0; ks < 2; ++ks) {
      bf16x8 pf = *(const bf16x8*)&Ps[w][ln][ks * 32 + kq8];
      l_acc = __builtin_amdgcn_mfma_f32_16x16x32_bf16(pf, ones, l_acc, 0, 0, 0);
#pragma unroll
      for (int j = 0; j < 4; ++j) {
        bf16x8 vf = *(const bf16x8*)(vbase + (size_t)(j * 16 + ln) * T_SZ +
                                     c0 + ks * 32 + kq8);
        O[j] = __builtin_amdgcn_mfma_f32_16x16x32_bf16(pf, vf, O[j], 0, 0, 0);
      }
    }
  }
  u16* op = outp + (size_t)b * T_SZ * 256;
#pragma unroll
  for (int r = 0; r < 4; ++r) {
    const float inv = 1.f / l_acc[r];
#pragma unroll
    for (int j = 0; j < 4; ++j)
      op[(size_t)(q0 + quad * 4 + r) * 256 + h * 64 + j * 16 + ln] =
          f2bf(O[j][r] * inv);
  }
}

// ---------------------------------------------------------------------------
// LayerNorm + misc elementwise (fp32 math)
// ---------------------------------------------------------------------------
__device__ __forceinline__ float block_reduce_sum(float v, float* tmp) {
#pragma unroll
  for (int o = 32; o > 0; o >>= 1) v += __shfl_down(v, o);
  const int lane = threadIdx.x & 63, wid = threadIdx.x >> 6;
  if (lane == 0) tmp[wid] = v;
  __syncthreads();
  v = tmp[0] + tmp[1] + tmp[2] + tmp[3];
  __syncthreads();
  return v;
}

__device__ __forceinline__ float ln_finish(float v, float s1, float s2,
                                           float g, float bb) {
  float mean = s1 * (1.f / 256.f);
  float var = s2 * (1.f / 256.f) - mean * mean;
  return (v - mean) * rsqrtf(var + 1e-5f) * g + bb;
}

__global__ __launch_bounds__(256)
void ln_add_kernel(const float* __restrict__ a, const float* __restrict__ addsrc,
                   const float* __restrict__ g, const float* __restrict__ bb,
                   float* __restrict__ outp) {
  __shared__ float tmp[4];
  const size_t row = blockIdx.x;
  const int d = threadIdx.x;
  float v = a[row * 256 + d] + addsrc[row * 256 + d];
  float s1 = block_reduce_sum(v, tmp);
  float s2 = block_reduce_sum(v * v, tmp);
  outp[row * 256 + d] = ln_finish(v, s1, s2, g[d], bb[d]);
}

__global__ __launch_bounds__(256)
void ln3_states_kernel(const float* __restrict__ deltas, const float* __restrict__ scr,
                       const float* __restrict__ seq, const float* __restrict__ g,
                       const float* __restrict__ bb, u16* __restrict__ st) {
  __shared__ float tmp[4];
  const int row = blockIdx.x;
  const int b = row >> 10, t = row & 1023;
  const int d = threadIdx.x;
  float v = seq[b * 256 + d] +
            0.5f * (deltas[(size_t)row * 256 + d] +
                    scr[(size_t)(b * 32 + (t >> 5)) * 256 + d]);
  float s1 = block_reduce_sum(v, tmp);
  float s2 = block_reduce_sum(v * v, tmp);
  st[(size_t)row * 256 + d] = f2bf(ln_finish(v, s1, s2, g[d], bb[d]));
}

__global__ __launch_bounds__(256)
void ln4_kernel(const u16* __restrict__ st, const float* __restrict__ g,
                const float* __restrict__ bb, float* __restrict__ outp) {
  __shared__ float tmp[4];
  const int b = blockIdx.x, d = threadIdx.x;
  float v = bf2f(st[(size_t)(b * T_SZ + 1023) * 256 + d]);
  float s1 = block_reduce_sum(v, tmp);
  float s2 = block_reduce_sum(v * v, tmp);
  outp[b * 256 + d] = ln_finish(v, s1, s2, g[d], bb[d]);
}

// ---------------------------------------------------------------------------
// Fused depthwise conv (window 8) + EMA local pass.
// Block (b, chunk of 32 t). Writes comb[:,256:512] (conv) and
// comb[:,512:768] (local EMA), plus chunk EMA carry to scr.
// ---------------------------------------------------------------------------
__global__ __launch_bounds__(256)
void emaconv_kernel(const float* __restrict__ x, const float* __restrict__ cw,
                    const float* __restrict__ cb, u16* __restrict__ comb,
                    float* __restrict__ scr) {
  const int bc = blockIdx.x;
  const int b = bc >> 5, ch = bc & 31;
  const int d = threadIdx.x;
  const int t0 = ch * 32;
  float wreg[8];
#pragma unroll
  for (int j = 0; j < 8; ++j) wreg[j] = cw[d * 8 + j];
  const float bias = cb[d];
  float xw[8];
#pragma unroll
  for (int j = 0; j < 7; ++j) {
    const int ts = t0 - 7 + j;
    xw[j] = (ts >= 0) ? x[(size_t)(b * T_SZ + ts) * 256 + d] : 0.f;
  }
  float c = 0.f;
#pragma unroll
  for (int tl = 0; tl < 32; ++tl) {
    const size_t row = (size_t)(b * T_SZ + t0 + tl);
    xw[7] = x[row * 256 + d];
    float conv = bias;
#pragma unroll
    for (int j = 0; j < 8; ++j) conv = fmaf(xw[j], wreg[j], conv);
    c = 0.9f * c + 0.1f * xw[7];
    comb[row * 768 + 256 + d] = f2bf(conv);
    comb[row * 768 + 512 + d] = f2bf(c);
#pragma unroll
    for (int j = 0; j < 7; ++j) xw[j] = xw[j + 1];
  }
  scr[(size_t)bc * 256 + d] = c;
}

__global__ __launch_bounds__(256)
void ema_b_kernel(float* __restrict__ scr) {
  const int b = blockIdx.x, d = threadIdx.x;
  const float q32 = 0.03433683820292512f;  // 0.9^32
  float carry = 0.f;
  for (int ch = 0; ch < 32; ++ch) {
    const size_t idx = (size_t)(b * 32 + ch) * 256 + d;
    float e = scr[idx];
    scr[idx] = carry;
    carry = e + q32 * carry;
  }
}

__global__ __launch_bounds__(256)
void ema_c_kernel(u16* __restrict__ comb, const float* __restrict__ scr,
                  float* __restrict__ fts) {
  const int row = blockIdx.x;
  const int b = row >> 10, t = row & 1023;
  const int d = threadIdx.x;
  const int ch = t >> 5, tl = t & 31;
  float carry = scr[(size_t)(b * 32 + ch) * 256 + d];
  float l = bf2f(comb[(size_t)row * 768 + 512 + d]);
  float y = fmaf(__powf(0.9f, (float)(tl + 1)), carry, l);
  comb[(size_t)row * 768 + 512 + d] = f2bf(y);
  if (t == 1023) fts[b * 256 + d] = y;
}

__global__ __launch_bounds__(256)
void cs_a_kernel(float* __restrict__ deltas, float* __restrict__ scr) {
  const int bc = blockIdx.x;
  const int b = bc >> 5, ch = bc & 31;
  const int d = threadIdx.x;
  const int t0 = ch * 32;
  float c = 0.f;
  for (int tl = 0; tl < 32; ++tl) {
    const size_t idx = (size_t)(b * T_SZ + t0 + tl) * 256 + d;
    c += deltas[idx];
    deltas[idx] = c;
  }
  scr[(size_t)bc * 256 + d] = c;
}

__global__ __launch_bounds__(256)
void cs_b_kernel(float* __restrict__ scr) {
  const int b = blockIdx.x, d = threadIdx.x;
  float carry = 0.f;
  for (int ch = 0; ch < 32; ++ch) {
    const size_t idx = (size_t)(b * 32 + ch) * 256 + d;
    float e = scr[idx];
    scr[idx] = carry;
    carry += e;
  }
}

// ---------------------------------------------------------------------------
extern "C" void kernel_launch(void* const* d_in, const int* in_sizes, int n_in,
                              void* d_out, int out_size, void* d_ws,
                              size_t ws_size, hipStream_t stream) {
  (void)in_sizes; (void)n_in; (void)out_size; (void)ws_size;
  const float* parallel_repr = (const float*)d_in[0];
  const float* sequential_state = (const float*)d_in[1];
  const float* in_proj_w = (const float*)d_in[3];
  const float* in_proj_b = (const float*)d_in[4];
  const float* out_proj_w = (const float*)d_in[5];
  const float* out_proj_b = (const float*)d_in[6];
  const float* conv_w = (const float*)d_in[7];
  const float* conv_b = (const float*)d_in[8];
  const float* p2s_w = (const float*)d_in[9];
  const float* p2s_b = (const float*)d_in[10];
  const float* s2p_w = (const float*)d_in[11];
  const float* s2p_b = (const float*)d_in[12];
  const float* trans_w1 = (const float*)d_in[13];
  const float* trans_b1 = (const float*)d_in[14];
  const float* trans_w2 = (const float*)d_in[15];
  const float* trans_b2 = (const float*)d_in[16];
  const float* ffn_w1 = (const float*)d_in[17];
  const float* ffn_b1 = (const float*)d_in[18];
  const float* ffn_w2 = (const float*)d_in[19];
  const float* ffn_b2 = (const float*)d_in[20];
  const float* ln1_s = (const float*)d_in[21];
  const float* ln1_b = (const float*)d_in[22];
  const float* ln2_s = (const float*)d_in[23];
  const float* ln2_b = (const float*)d_in[24];
  const float* ln3_s = (const float*)d_in[25];
  const float* ln3_b = (const float*)d_in[26];
  const float* ln4_s = (const float*)d_in[27];
  const float* ln4_b = (const float*)d_in[28];

  char* ws = (char*)d_ws;
  u16* qkv_bf = (u16*)(ws + OFF_QKV);
  u16* attn_bf = (u16*)(ws + OFF_ATTN);
  u16* states_bf = (u16*)(ws + OFF_ATTN);
  u16* f_bf = (u16*)(ws + OFF_F);
  float* x = (float*)(ws + OFF_X);
  u16* comb = (u16*)(ws + OFF_COMB);
  u16* ffn_in = (u16*)(ws + OFF_COMB);
  float* fbuf = (float*)(ws + OFF_FB);
  u16* vt = (u16*)(ws + OFF_H);    // 4MB, dead before h is written
  u16* h_bf = (u16*)(ws + OFF_H);
  u16* wb = (u16*)(ws + OFF_WB);
  float* scr1 = (float*)(ws + OFF_SCR1);
  float* scr2 = (float*)(ws + OFF_SCR2);
  float* out = (float*)d_out;
  float* out_fss = out + S_ELT;
  float* out_fts = out + S_ELT + 2048;

  const dim3 blk(256);

  // 0. weights -> bf16
  wconv_kernel<<<1408, blk, 0, stream>>>(in_proj_w, out_proj_w, p2s_w, s2p_w,
                                         trans_w1, trans_w2, ffn_w1, ffn_w2, wb);
  // 1. qkv = PR @ in_proj^T + b
  mgemm<EPI_NONE, 128, true, true><<<dim3(64, 6), blk, 0, stream>>>(
      parallel_repr, 256, wb + WB_INPROJ, 256, in_proj_b, qkv_bf, 768, 0, nullptr);
  // 2a. V transpose
  vtr_kernel<<<dim3(16, 32), blk, 0, stream>>>(qkv_bf, vt);
  // 2b. attention (barrier-free)
  attn_flash<<<512, blk, 0, stream>>>(qkv_bf, vt, attn_bf);
  // 3. attn_out = attn @ out_proj^T + b -> fbuf (fp32)
  mgemm<EPI_NONE, 64, false, false><<<dim3(64, 4), blk, 0, stream>>>(
      attn_bf, 256, wb + WB_OUTPROJ, 256, out_proj_b, fbuf, 256, 0, nullptr);
  // 4. x = LN1(PR + attn_out)
  ln_add_kernel<<<8192, blk, 0, stream>>>(parallel_repr, fbuf, ln1_s, ln1_b, x);
  // 5-7. fused conv+EMA -> comb[:,256:768] + traj summary
  emaconv_kernel<<<256, blk, 0, stream>>>(x, conv_w, conv_b, comb, scr1);
  ema_b_kernel<<<8, blk, 0, stream>>>(scr1);
  ema_c_kernel<<<8192, blk, 0, stream>>>(comb, scr1, out_fts);
  // 8. comb[:,0:256] = x + 0.3*(x @ p2s^T + b)
  mgemm<EPI_ADDSCALE, 64, true, true><<<dim3(64, 4), blk, 0, stream>>>(
      x, 256, wb + WB_P2S, 256, p2s_b, comb, 768, 0, x);
  // 9. h = gelu(comb @ t1^T + b1)
  mgemm<EPI_GELU, 128, true, false><<<dim3(64, 4), blk, 0, stream>>>(
      comb, 768, wb + WB_T1, 768, trans_b1, h_bf, 512, 0, nullptr);
  // 10. deltas = h @ t2^T + b2 -> fbuf (fp32)
  mgemm<EPI_NONE, 64, false, false><<<dim3(64, 4), blk, 0, stream>>>(
      h_bf, 512, wb + WB_T2, 512, trans_b2, fbuf, 256, 0, nullptr);
  // 11-12. cumsum
  cs_a_kernel<<<256, blk, 0, stream>>>(fbuf, scr2);
  cs_b_kernel<<<8, blk, 0, stream>>>(scr2);
  // 13. states = LN3(...) -> bf16
  ln3_states_kernel<<<8192, blk, 0, stream>>>(fbuf, scr2, sequential_state,
                                              ln3_s, ln3_b, states_bf);
  // 14. fss = LN4(states[:,-1])
  ln4_kernel<<<8, blk, 0, stream>>>(states_bf, ln4_s, ln4_b, out_fss);
  // 15. ffn_in = x + 0.3*(states @ s2p^T + b)
  mgemm<EPI_ADDSCALE, 64, true, false><<<dim3(64, 4), blk, 0, stream>>>(
      states_bf, 256, wb + WB_S2P, 256, s2p_b, ffn_in, 256, 0, x);
  // 16. f = gelu(ffn_in @ ffn1^T + b1)
  mgemm<EPI_GELU, 128, true, false><<<dim3(64, 8), blk, 0, stream>>>(
      ffn_in, 256, wb + WB_F1, 256, ffn_b1, f_bf, 1024, 0, nullptr);
  // 17. ffn_out = f @ ffn2^T + b2 -> fbuf
  mgemm<EPI_NONE, 64, false, false><<<dim3(64, 4), blk, 0, stream>>>(
      f_bf, 1024, wb + WB_F2, 1024, ffn_b2, fbuf, 256, 0, nullptr);
  // 18. out = LN2(x + ffn_out)
  ln_add_kernel<<<8192, blk, 0, stream>>>(x, fbuf, ln2_s, ln2_b, out);
}

// Round 4
// 303.252 us; speedup vs baseline: 2.5215x; 1.0434x over previous
//
#include <hip/hip_runtime.h>
#include <math.h>

typedef unsigned short u16;
typedef __attribute__((ext_vector_type(8))) short bf16x8;
typedef __attribute__((ext_vector_type(4))) float f32x4;

#define D_MODEL 256
#define T_SZ 1024
constexpr size_t S_ELT = (size_t)8192 * 256;
constexpr size_t MB = 1024 * 1024;

// workspace byte offsets (56MB footprint)
constexpr size_t OFF_QKV = 0;          // u16 [8192][768] (12MB); later f overlays [0,16MB)
constexpr size_t OFF_ATTN = 12 * MB;   // u16 [8192][256] (4MB); later states_bf
constexpr size_t OFF_F = 0;            // u16 [8192][1024] (16MB)
constexpr size_t OFF_X = 16 * MB;      // f32 [8192][256] (8MB)
constexpr size_t OFF_COMB = 24 * MB;   // u16 [8192][768] (12MB); pr_bf + later ffn_in overlay head
constexpr size_t OFF_FB = 36 * MB;     // f32 [8192][256]: attn_out -> deltas -> ffn_out
constexpr size_t OFF_H = 44 * MB;      // u16: vt (4MB, dead after attn) then h (8MB)
constexpr size_t OFF_XBF = 48 * MB;    // u16 x_bf (4MB); overwritten by h tail at step 9
constexpr size_t OFF_WB = 52 * MB;     // u16 weights (2.75MB)
constexpr size_t OFF_SCR1 = 55 * MB;           // f32 65536
constexpr size_t OFF_SCR2 = 55 * MB + 262144;  // f32 65536

// bf16 weight element offsets inside WB
constexpr int WB_INPROJ = 0;
constexpr int WB_OUTPROJ = 196608;
constexpr int WB_P2S = 262144;
constexpr int WB_S2P = 327680;
constexpr int WB_T1 = 393216;
constexpr int WB_T2 = 786432;
constexpr int WB_F1 = 917504;
constexpr int WB_F2 = 1179648;
constexpr int WB_TOTAL = 1441792;

__device__ __forceinline__ u16 f2bf(float f) {
  unsigned int u = __float_as_uint(f);
  u += 0x7fff + ((u >> 16) & 1);
  return (u16)(u >> 16);
}
__device__ __forceinline__ float bf2f(u16 s) {
  return __uint_as_float(((unsigned int)s) << 16);
}

// async global -> LDS, 16B per lane; LDS dst must be wave-uniform base.
__device__ __forceinline__ void glds16(const u16* g, u16* l) {
  __builtin_amdgcn_global_load_lds(
      (const __attribute__((address_space(1))) void*)g,
      (__attribute__((address_space(3))) void*)l, 16, 0, 0);
}

// ---------------------------------------------------------------------------
// weight fp32 -> bf16 conversion
// ---------------------------------------------------------------------------
__global__ __launch_bounds__(256)
void wconv_kernel(const float* w0, const float* w1, const float* w2,
                  const float* w3, const float* w4, const float* w5,
                  const float* w6, const float* w7, u16* __restrict__ outp) {
  const int idx4 = (blockIdx.x * 256 + threadIdx.x) * 4;
  if (idx4 >= WB_TOTAL) return;
  const int offs[9] = {WB_INPROJ, WB_OUTPROJ, WB_P2S,  WB_S2P, WB_T1,
                       WB_T2,     WB_F1,      WB_F2,   WB_TOTAL};
  const float* srcs[8] = {w0, w1, w2, w3, w4, w5, w6, w7};
  int seg = 0;
  while (idx4 >= offs[seg + 1]) ++seg;
  float4 v = *(const float4*)(srcs[seg] + (idx4 - offs[seg]));
  unsigned int lo = (unsigned int)f2bf(v.x) | ((unsigned int)f2bf(v.y) << 16);
  unsigned int hi = (unsigned int)f2bf(v.z) | ((unsigned int)f2bf(v.w) << 16);
  *(uint2*)(outp + idx4) = make_uint2(lo, hi);
}

__global__ __launch_bounds__(256)
void cvtbf_kernel(const float* __restrict__ src, u16* __restrict__ dst) {
  const int i4 = (blockIdx.x * 256 + threadIdx.x) * 4;
  float4 v = *(const float4*)(src + i4);
  unsigned int lo = (unsigned int)f2bf(v.x) | ((unsigned int)f2bf(v.y) << 16);
  unsigned int hi = (unsigned int)f2bf(v.z) | ((unsigned int)f2bf(v.w) << 16);
  *(uint2*)(dst + i4) = make_uint2(lo, hi);
}

// ---------------------------------------------------------------------------
// bf16 MFMA GEMM, m97-style: async global_load_lds staging into a
// fragment-ordered contiguous LDS layout (16-row group g occupies the 1KB
// block [g*1024, (g+1)*1024), element (row,cg) at g*512 + (row&15)*32 + cg*8
// u16), so both the DMA (lane*16B) and the ds_read_b128 fragment reads are
// contiguous & conflict-free. 2-barrier K-loop, BK=32.
// ---------------------------------------------------------------------------
enum { EPI_NONE = 0, EPI_GELU = 1, EPI_ADDSCALE = 2 };

template <int EPI, int BM, int BN, bool OUTBF>
__global__ __launch_bounds__(256)
void mgemm(const u16* __restrict__ A, int lda,
           const u16* __restrict__ Wb, int K, const float* __restrict__ bias,
           void* __restrict__ Cv, int ldc, int col_off,
           const float* __restrict__ addsrc) {
  __shared__ u16 As[BM * 32];
  __shared__ u16 Bs[BN * 32];
  const int tid = threadIdx.x;
  const int w = tid >> 6, lane = tid & 63;
  const int ln = lane & 15, quad = lane >> 4;
  const int m0 = blockIdx.x * BM;
  const int n0 = blockIdx.y * BN;
  // wave tile assignment
  constexpr int MT = (BM == 128 && BN == 128) ? 4 : (BM == 128 ? 2 : 1);
  const int wm = (BM == 128 && BN == 128) ? (w >> 1) * 64
                 : (BM == 128)            ? w * 32
                                          : w * 16;
  const int wn = (BM == 128 && BN == 128) ? (w & 1) * 64 : 0;
  constexpr int APW = BM / 64;  // A groups per wave (GA=BM/16, 4 waves)
  constexpr int BPW = BN / 64;

  f32x4 acc[MT][4] = {};

  const int grow = lane >> 2;            // row within 16-row group
  const int gk8 = (lane & 3) * 8;        // k element offset

  for (int k0 = 0; k0 < K; k0 += 32) {
    // async staging
#pragma unroll
    for (int p = 0; p < APW; ++p) {
      const int g = w * APW + p;
      glds16(A + (size_t)(m0 + g * 16 + grow) * lda + k0 + gk8, As + g * 512);
    }
#pragma unroll
    for (int p = 0; p < BPW; ++p) {
      const int g = w * BPW + p;
      glds16(Wb + (size_t)(n0 + g * 16 + grow) * K + k0 + gk8, Bs + g * 512);
    }
    __syncthreads();  // drains vmcnt -> LDS valid

    const u16* abase = As + (wm >> 4) * 512 + ln * 32 + quad * 8;
    const u16* bbase = Bs + (wn >> 4) * 512 + ln * 32 + quad * 8;
    bf16x8 af[MT], bv[4];
#pragma unroll
    for (int i = 0; i < MT; ++i) af[i] = *(const bf16x8*)(abase + i * 512);
#pragma unroll
    for (int j = 0; j < 4; ++j) bv[j] = *(const bf16x8*)(bbase + j * 512);
#pragma unroll
    for (int i = 0; i < MT; ++i)
#pragma unroll
      for (int j = 0; j < 4; ++j)
        acc[i][j] =
            __builtin_amdgcn_mfma_f32_16x16x32_bf16(af[i], bv[j], acc[i][j], 0, 0, 0);
    __syncthreads();  // protect LDS reuse next iter
  }

#pragma unroll
  for (int i = 0; i < MT; ++i)
#pragma unroll
    for (int j = 0; j < 4; ++j) {
      const int col = n0 + wn + j * 16 + ln;
      const float bsv = bias[col];
#pragma unroll
      for (int r = 0; r < 4; ++r) {
        const int row = m0 + wm + i * 16 + quad * 4 + r;
        float v = acc[i][j][r] + bsv;
        if (EPI == EPI_GELU) v = 0.5f * v * (1.0f + erff(v * 0.70710678f));
        if (EPI == EPI_ADDSCALE) v = addsrc[(size_t)row * 256 + col] + 0.3f * v;
        if (OUTBF)
          ((u16*)Cv)[(size_t)row * ldc + col_off + col] = f2bf(v);
        else
          ((float*)Cv)[(size_t)row * ldc + col_off + col] = v;
      }
    }
}

// ---------------------------------------------------------------------------
// V transpose: qkv[b][t][512 + h*64 + d] -> vt[(b*4+h)*64 + d][t]
// ---------------------------------------------------------------------------
__global__ __launch_bounds__(256)
void vtr_kernel(const u16* __restrict__ qkv, u16* __restrict__ vt) {
  __shared__ u16 Ls[64][66];
  const int tid = threadIdx.x;
  const int t0 = blockIdx.x * 64;
  const int bh = blockIdx.y;
  const int b = bh >> 2, h = bh & 3;
  const int r0 = tid >> 3, c8 = (tid & 7) * 8;
#pragma unroll
  for (int p = 0; p < 2; ++p) {
    const int t = t0 + r0 + p * 32;
    *(uint4*)&Ls[r0 + p * 32][c8] =
        *(const uint4*)(qkv + (size_t)(b * T_SZ + t) * 768 + 512 + h * 64 + c8);
  }
  __syncthreads();
#pragma unroll
  for (int p = 0; p < 2; ++p) {
    const int d = r0 + p * 32;
    union { u16 h16[8]; uint4 u; } pk;
#pragma unroll
    for (int e = 0; e < 8; ++e) pk.h16[e] = Ls[c8 + e][d];
    *(uint4*)(vt + (size_t)(bh * 64 + d) * T_SZ + t0 + c8) = pk.u;
  }
}

// ---------------------------------------------------------------------------
// Barrier-free MFMA flash attention (one wave = 16 q rows, paired balance).
// ---------------------------------------------------------------------------
__global__ __launch_bounds__(256)
void attn_flash(const u16* __restrict__ qkv, const u16* __restrict__ vt,
                u16* __restrict__ outp) {
  __shared__ u16 Ps[4][16][72];
  const int tid = threadIdx.x;
  const int w = tid >> 6, lane = tid & 63;
  const int ln = lane & 15, quad = lane >> 4, kq8 = quad * 8;
  const int wu = blockIdx.x * 4 + w;
  const int bh = wu >> 6, s = wu & 63;
  const int qt = (s & 1) ? (63 - (s >> 1)) : (s >> 1);
  const int q0 = qt * 16;
  const int b = bh >> 2, h = bh & 3;
  const u16* base = qkv + (size_t)b * T_SZ * 768;
  const u16* vbase = vt + (size_t)bh * 64 * T_SZ;

  bf16x8 qf[2];
#pragma unroll
  for (int ks = 0; ks < 2; ++ks)
    qf[ks] = *(const bf16x8*)(base + (size_t)(q0 + ln) * 768 + h * 64 +
                              ks * 32 + kq8);
  const short ob = (short)0x3F80;
  const bf16x8 ones = {ob, ob, ob, ob, ob, ob, ob, ob};

  f32x4 O[4] = {};
  f32x4 l_acc = {};
  const int ntiles = (qt >> 2) + 1;
  for (int jt = 0; jt < ntiles; ++jt) {
    const int c0 = jt * 64;
    f32x4 sv[4] = {};
#pragma unroll
    for (int ks = 0; ks < 2; ++ks)
#pragma unroll
      for (int j = 0; j < 4; ++j) {
        bf16x8 kf = *(const bf16x8*)(base + (size_t)(c0 + j * 16 + ln) * 768 +
                                     256 + h * 64 + ks * 32 + kq8);
        sv[j] = __builtin_amdgcn_mfma_f32_16x16x32_bf16(qf[ks], kf, sv[j], 0, 0, 0);
      }
    const bool need_mask = (c0 + 63 > q0);
#pragma unroll
    for (int j = 0; j < 4; ++j)
#pragma unroll
      for (int r = 0; r < 4; ++r) {
        float p = __expf(sv[j][r] * 0.125f);
        if (need_mask && (c0 + j * 16 + ln > q0 + quad * 4 + r)) p = 0.f;
        Ps[w][quad * 4 + r][j * 16 + ln] = f2bf(p);
      }
#pragma unroll
    for (int ks = 0; ks < 2; ++ks) {
      bf16x8 pf = *(const bf16x8*)&Ps[w][ln][ks * 32 + kq8];
      l_acc = __builtin_amdgcn_mfma_f32_16x16x32_bf16(pf, ones, l_acc, 0, 0, 0);
#pragma unroll
      for (int j = 0; j < 4; ++j) {
        bf16x8 vf = *(const bf16x8*)(vbase + (size_t)(j * 16 + ln) * T_SZ +
                                     c0 + ks * 32 + kq8);
        O[j] = __builtin_amdgcn_mfma_f32_16x16x32_bf16(pf, vf, O[j], 0, 0, 0);
      }
    }
  }
  u16* op = outp + (size_t)b * T_SZ * 256;
#pragma unroll
  for (int r = 0; r < 4; ++r) {
    const float inv = 1.f / l_acc[r];
#pragma unroll
    for (int j = 0; j < 4; ++j)
      op[(size_t)(q0 + quad * 4 + r) * 256 + h * 64 + j * 16 + ln] =
          f2bf(O[j][r] * inv);
  }
}

// ---------------------------------------------------------------------------
// LayerNorm + misc elementwise (fp32 math)
// ---------------------------------------------------------------------------
__device__ __forceinline__ float block_reduce_sum(float v, float* tmp) {
#pragma unroll
  for (int o = 32; o > 0; o >>= 1) v += __shfl_down(v, o);
  const int lane = threadIdx.x & 63, wid = threadIdx.x >> 6;
  if (lane == 0) tmp[wid] = v;
  __syncthreads();
  v = tmp[0] + tmp[1] + tmp[2] + tmp[3];
  __syncthreads();
  return v;
}

__device__ __forceinline__ float ln_finish(float v, float s1, float s2,
                                           float g, float bb) {
  float mean = s1 * (1.f / 256.f);
  float var = s2 * (1.f / 256.f) - mean * mean;
  return (v - mean) * rsqrtf(var + 1e-5f) * g + bb;
}

__global__ __launch_bounds__(256)
void ln_add_kernel(const float* __restrict__ a, const float* __restrict__ addsrc,
                   const float* __restrict__ g, const float* __restrict__ bb,
                   float* __restrict__ outp, u16* __restrict__ obf) {
  __shared__ float tmp[4];
  const size_t row = blockIdx.x;
  const int d = threadIdx.x;
  float v = a[row * 256 + d] + addsrc[row * 256 + d];
  float s1 = block_reduce_sum(v, tmp);
  float s2 = block_reduce_sum(v * v, tmp);
  float y = ln_finish(v, s1, s2, g[d], bb[d]);
  outp[row * 256 + d] = y;
  if (obf) obf[row * 256 + d] = f2bf(y);
}

__global__ __launch_bounds__(256)
void ln3_states_kernel(const float* __restrict__ deltas, const float* __restrict__ scr,
                       const float* __restrict__ seq, const float* __restrict__ g,
                       const float* __restrict__ bb, u16* __restrict__ st) {
  __shared__ float tmp[4];
  const int row = blockIdx.x;
  const int b = row >> 10, t = row & 1023;
  const int d = threadIdx.x;
  float v = seq[b * 256 + d] +
            0.5f * (deltas[(size_t)row * 256 + d] +
                    scr[(size_t)(b * 32 + (t >> 5)) * 256 + d]);
  float s1 = block_reduce_sum(v, tmp);
  float s2 = block_reduce_sum(v * v, tmp);
  st[(size_t)row * 256 + d] = f2bf(ln_finish(v, s1, s2, g[d], bb[d]));
}

__global__ __launch_bounds__(256)
void ln4_kernel(const u16* __restrict__ st, const float* __restrict__ g,
                const float* __restrict__ bb, float* __restrict__ outp) {
  __shared__ float tmp[4];
  const int b = blockIdx.x, d = threadIdx.x;
  float v = bf2f(st[(size_t)(b * T_SZ + 1023) * 256 + d]);
  float s1 = block_reduce_sum(v, tmp);
  float s2 = block_reduce_sum(v * v, tmp);
  outp[b * 256 + d] = ln_finish(v, s1, s2, g[d], bb[d]);
}

// ---------------------------------------------------------------------------
// Fused depthwise conv (window 8) + EMA local pass.
// ---------------------------------------------------------------------------
__global__ __launch_bounds__(256)
void emaconv_kernel(const float* __restrict__ x, const float* __restrict__ cw,
                    const float* __restrict__ cb, u16* __restrict__ comb,
                    float* __restrict__ scr) {
  const int bc = blockIdx.x;
  const int b = bc >> 5, ch = bc & 31;
  const int d = threadIdx.x;
  const int t0 = ch * 32;
  float wreg[8];
#pragma unroll
  for (int j = 0; j < 8; ++j) wreg[j] = cw[d * 8 + j];
  const float bias = cb[d];
  float xw[8];
#pragma unroll
  for (int j = 0; j < 7; ++j) {
    const int ts = t0 - 7 + j;
    xw[j] = (ts >= 0) ? x[(size_t)(b * T_SZ + ts) * 256 + d] : 0.f;
  }
  float c = 0.f;
#pragma unroll
  for (int tl = 0; tl < 32; ++tl) {
    const size_t row = (size_t)(b * T_SZ + t0 + tl);
    xw[7] = x[row * 256 + d];
    float conv = bias;
#pragma unroll
    for (int j = 0; j < 8; ++j) conv = fmaf(xw[j], wreg[j], conv);
    c = 0.9f * c + 0.1f * xw[7];
    comb[row * 768 + 256 + d] = f2bf(conv);
    comb[row * 768 + 512 + d] = f2bf(c);
#pragma unroll
    for (int j = 0; j < 7; ++j) xw[j] = xw[j + 1];
  }
  scr[(size_t)bc * 256 + d] = c;
}

__global__ __launch_bounds__(256)
void ema_b_kernel(float* __restrict__ scr) {
  const int b = blockIdx.x, d = threadIdx.x;
  const float q32 = 0.03433683820292512f;  // 0.9^32
  float carry = 0.f;
  for (int ch = 0; ch < 32; ++ch) {
    const size_t idx = (size_t)(b * 32 + ch) * 256 + d;
    float e = scr[idx];
    scr[idx] = carry;
    carry = e + q32 * carry;
  }
}

__global__ __launch_bounds__(256)
void ema_c_kernel(u16* __restrict__ comb, const float* __restrict__ scr,
                  float* __restrict__ fts) {
  const int row = blockIdx.x;
  const int b = row >> 10, t = row & 1023;
  const int d = threadIdx.x;
  const int ch = t >> 5, tl = t & 31;
  float carry = scr[(size_t)(b * 32 + ch) * 256 + d];
  float l = bf2f(comb[(size_t)row * 768 + 512 + d]);
  float y = fmaf(__powf(0.9f, (float)(tl + 1)), carry, l);
  comb[(size_t)row * 768 + 512 + d] = f2bf(y);
  if (t == 1023) fts[b * 256 + d] = y;
}

__global__ __launch_bounds__(256)
void cs_a_kernel(float* __restrict__ deltas, float* __restrict__ scr) {
  const int bc = blockIdx.x;
  const int b = bc >> 5, ch = bc & 31;
  const int d = threadIdx.x;
  const int t0 = ch * 32;
  float c = 0.f;
  for (int tl = 0; tl < 32; ++tl) {
    const size_t idx = (size_t)(b * T_SZ + t0 + tl) * 256 + d;
    c += deltas[idx];
    deltas[idx] = c;
  }
  scr[(size_t)bc * 256 + d] = c;
}

__global__ __launch_bounds__(256)
void cs_b_kernel(float* __restrict__ scr) {
  const int b = blockIdx.x, d = threadIdx.x;
  float carry = 0.f;
  for (int ch = 0; ch < 32; ++ch) {
    const size_t idx = (size_t)(b * 32 + ch) * 256 + d;
    float e = scr[idx];
    scr[idx] = carry;
    carry += e;
  }
}

// ---------------------------------------------------------------------------
extern "C" void kernel_launch(void* const* d_in, const int* in_sizes, int n_in,
                              void* d_out, int out_size, void* d_ws,
                              size_t ws_size, hipStream_t stream) {
  (void)in_sizes; (void)n_in; (void)out_size; (void)ws_size;
  const float* parallel_repr = (const float*)d_in[0];
  const float* sequential_state = (const float*)d_in[1];
  const float* in_proj_b = (const float*)d_in[4];
  const float* out_proj_b = (const float*)d_in[6];
  const float* conv_w = (const float*)d_in[7];
  const float* conv_b = (const float*)d_in[8];
  const float* p2s_b = (const float*)d_in[10];
  const float* s2p_b = (const float*)d_in[12];
  const float* trans_b1 = (const float*)d_in[14];
  const float* trans_b2 = (const float*)d_in[16];
  const float* ffn_b1 = (const float*)d_in[18];
  const float* ffn_b2 = (const float*)d_in[20];
  const float* ln1_s = (const float*)d_in[21];
  const float* ln1_b = (const float*)d_in[22];
  const float* ln2_s = (const float*)d_in[23];
  const float* ln2_b = (const float*)d_in[24];
  const float* ln3_s = (const float*)d_in[25];
  const float* ln3_b = (const float*)d_in[26];
  const float* ln4_s = (const float*)d_in[27];
  const float* ln4_b = (const float*)d_in[28];

  char* ws = (char*)d_ws;
  u16* qkv_bf = (u16*)(ws + OFF_QKV);
  u16* attn_bf = (u16*)(ws + OFF_ATTN);
  u16* states_bf = (u16*)(ws + OFF_ATTN);
  u16* f_bf = (u16*)(ws + OFF_F);
  float* x = (float*)(ws + OFF_X);
  u16* comb = (u16*)(ws + OFF_COMB);
  u16* pr_bf = (u16*)(ws + OFF_COMB);  // dead before comb is written
  u16* ffn_in = (u16*)(ws + OFF_COMB); // overlay after comb consumed
  float* fbuf = (float*)(ws + OFF_FB);
  u16* vt = (u16*)(ws + OFF_H);        // dead before h is written
  u16* h_bf = (u16*)(ws + OFF_H);
  u16* x_bf = (u16*)(ws + OFF_XBF);    // dead after step 8 (h overwrites)
  u16* wb = (u16*)(ws + OFF_WB);
  float* scr1 = (float*)(ws + OFF_SCR1);
  float* scr2 = (float*)(ws + OFF_SCR2);
  float* out = (float*)d_out;
  float* out_fss = out + S_ELT;
  float* out_fts = out + S_ELT + 2048;

  const dim3 blk(256);

  // 0. weights + parallel_repr -> bf16
  wconv_kernel<<<1408, blk, 0, stream>>>(
      (const float*)d_in[3], (const float*)d_in[5], (const float*)d_in[9],
      (const float*)d_in[11], (const float*)d_in[13], (const float*)d_in[15],
      (const float*)d_in[17], (const float*)d_in[19], wb);
  cvtbf_kernel<<<2048, blk, 0, stream>>>(parallel_repr, pr_bf);
  // 1. qkv = PR @ in_proj^T + b
  mgemm<EPI_NONE, 128, 128, true><<<dim3(64, 6), blk, 0, stream>>>(
      pr_bf, 256, wb + WB_INPROJ, 256, in_proj_b, qkv_bf, 768, 0, nullptr);
  // 2a. V transpose
  vtr_kernel<<<dim3(16, 32), blk, 0, stream>>>(qkv_bf, vt);
  // 2b. attention (barrier-free)
  attn_flash<<<512, blk, 0, stream>>>(qkv_bf, vt, attn_bf);
  // 3. attn_out = attn @ out_proj^T + b -> fbuf (fp32)
  mgemm<EPI_NONE, 64, 64, false><<<dim3(128, 4), blk, 0, stream>>>(
      attn_bf, 256, wb + WB_OUTPROJ, 256, out_proj_b, fbuf, 256, 0, nullptr);
  // 4. x = LN1(PR + attn_out), also emit x_bf
  ln_add_kernel<<<8192, blk, 0, stream>>>(parallel_repr, fbuf, ln1_s, ln1_b, x,
                                          x_bf);
  // 5-7. fused conv+EMA -> comb[:,256:768] + traj summary
  emaconv_kernel<<<256, blk, 0, stream>>>(x, conv_w, conv_b, comb, scr1);
  ema_b_kernel<<<8, blk, 0, stream>>>(scr1);
  ema_c_kernel<<<8192, blk, 0, stream>>>(comb, scr1, out_fts);
  // 8. comb[:,0:256] = x + 0.3*(x @ p2s^T + b)
  mgemm<EPI_ADDSCALE, 64, 64, true><<<dim3(128, 4), blk, 0, stream>>>(
      x_bf, 256, wb + WB_P2S, 256, p2s_b, comb, 768, 0, x);
  // 9. h = gelu(comb @ t1^T + b1)
  mgemm<EPI_GELU, 128, 128, true><<<dim3(64, 4), blk, 0, stream>>>(
      comb, 768, wb + WB_T1, 768, trans_b1, h_bf, 512, 0, nullptr);
  // 10. deltas = h @ t2^T + b2 -> fbuf (fp32)
  mgemm<EPI_NONE, 64, 64, false><<<dim3(128, 4), blk, 0, stream>>>(
      h_bf, 512, wb + WB_T2, 512, trans_b2, fbuf, 256, 0, nullptr);
  // 11-12. cumsum
  cs_a_kernel<<<256, blk, 0, stream>>>(fbuf, scr2);
  cs_b_kernel<<<8, blk, 0, stream>>>(scr2);
  // 13. states = LN3(...) -> bf16
  ln3_states_kernel<<<8192, blk, 0, stream>>>(fbuf, scr2, sequential_state,
                                              ln3_s, ln3_b, states_bf);
  // 14. fss = LN4(states[:,-1])
  ln4_kernel<<<8, blk, 0, stream>>>(states_bf, ln4_s, ln4_b, out_fss);
  // 15. ffn_in = x + 0.3*(states @ s2p^T + b)
  mgemm<EPI_ADDSCALE, 64, 64, true><<<dim3(128, 4), blk, 0, stream>>>(
      states_bf, 256, wb + WB_S2P, 256, s2p_b, ffn_in, 256, 0, x);
  // 16. f = gelu(ffn_in @ ffn1^T + b1)
  mgemm<EPI_GELU, 128, 128, true><<<dim3(64, 8), blk, 0, stream>>>(
      ffn_in, 256, wb + WB_F1, 256, ffn_b1, f_bf, 1024, 0, nullptr);
  // 17. ffn_out = f @ ffn2^T + b2 -> fbuf
  mgemm<EPI_NONE, 64, 64, false><<<dim3(128, 4), blk, 0, stream>>>(
      f_bf, 1024, wb + WB_F2, 1024, ffn_b2, fbuf, 256, 0, nullptr);
  // 18. out = LN2(x + ffn_out)
  ln_add_kernel<<<8192, blk, 0, stream>>>(x, fbuf, ln2_s, ln2_b, out, nullptr);
}

// Round 5
// 276.341 us; speedup vs baseline: 2.7670x; 1.0974x over previous
//
#include <hip/hip_runtime.h>
#include <math.h>

typedef unsigned short u16;
typedef __attribute__((ext_vector_type(8))) short bf16x8;
typedef __attribute__((ext_vector_type(4))) float f32x4;

#define D_MODEL 256
#define T_SZ 1024
constexpr size_t S_ELT = (size_t)8192 * 256;
constexpr size_t MB = 1024 * 1024;

// workspace byte offsets (56MB footprint)
constexpr size_t OFF_QKV = 0;          // u16 [8192][768] (12MB, V region unused); later f overlays [0,16MB)
constexpr size_t OFF_ATTN = 12 * MB;   // u16 [8192][256] (4MB); later states_bf
constexpr size_t OFF_F = 0;            // u16 [8192][1024] (16MB)
constexpr size_t OFF_X = 16 * MB;      // f32 [8192][256] (8MB)
constexpr size_t OFF_COMB = 24 * MB;   // u16 [8192][768] (12MB); pr_bf + later ffn_in overlay head
constexpr size_t OFF_FB = 36 * MB;     // f32 [8192][256]: attn_out -> deltas -> ffn_out
constexpr size_t OFF_H = 44 * MB;      // u16: vt (4MB, dead after attn) then h (8MB)
constexpr size_t OFF_XBF = 48 * MB;    // u16 x_bf (4MB)
constexpr size_t OFF_WB = 52 * MB;     // u16 weights (2.75MB)
constexpr size_t OFF_SCR1 = 55 * MB;           // f32 65536
constexpr size_t OFF_SCR2 = 55 * MB + 262144;  // f32 65536

// bf16 weight element offsets inside WB
constexpr int WB_INPROJ = 0;
constexpr int WB_OUTPROJ = 196608;
constexpr int WB_P2S = 262144;
constexpr int WB_S2P = 327680;
constexpr int WB_T1 = 393216;
constexpr int WB_T2 = 786432;
constexpr int WB_F1 = 917504;
constexpr int WB_F2 = 1179648;
constexpr int WB_TOTAL = 1441792;
constexpr int PR_TOTAL = 2097152;

__device__ __forceinline__ u16 f2bf(float f) {
  unsigned int u = __float_as_uint(f);
  u += 0x7fff + ((u >> 16) & 1);
  return (u16)(u >> 16);
}
__device__ __forceinline__ float bf2f(u16 s) {
  return __uint_as_float(((unsigned int)s) << 16);
}

// async global -> LDS, 16B per lane; LDS dst is wave-uniform base + lane*16B.
__device__ __forceinline__ void glds16(const u16* g, u16* l) {
  __builtin_amdgcn_global_load_lds(
      (const __attribute__((address_space(1))) void*)g,
      (__attribute__((address_space(3))) void*)l, 16, 0, 0);
}

// ---------------------------------------------------------------------------
// weight + parallel_repr fp32 -> bf16 conversion (single kernel)
// ---------------------------------------------------------------------------
__global__ __launch_bounds__(256)
void wconv_kernel(const float* w0, const float* w1, const float* w2,
                  const float* w3, const float* w4, const float* w5,
                  const float* w6, const float* w7, const float* pr,
                  u16* __restrict__ wb, u16* __restrict__ prb) {
  const int idx4 = (blockIdx.x * 256 + threadIdx.x) * 4;
  if (idx4 < WB_TOTAL) {
    const int offs[9] = {WB_INPROJ, WB_OUTPROJ, WB_P2S,  WB_S2P, WB_T1,
                         WB_T2,     WB_F1,      WB_F2,   WB_TOTAL};
    const float* srcs[8] = {w0, w1, w2, w3, w4, w5, w6, w7};
    int seg = 0;
    while (idx4 >= offs[seg + 1]) ++seg;
    float4 v = *(const float4*)(srcs[seg] + (idx4 - offs[seg]));
    unsigned int lo = (unsigned int)f2bf(v.x) | ((unsigned int)f2bf(v.y) << 16);
    unsigned int hi = (unsigned int)f2bf(v.z) | ((unsigned int)f2bf(v.w) << 16);
    *(uint2*)(wb + idx4) = make_uint2(lo, hi);
  } else {
    const int i4 = idx4 - WB_TOTAL;
    if (i4 < PR_TOTAL) {
      float4 v = *(const float4*)(pr + i4);
      unsigned int lo = (unsigned int)f2bf(v.x) | ((unsigned int)f2bf(v.y) << 16);
      unsigned int hi = (unsigned int)f2bf(v.z) | ((unsigned int)f2bf(v.w) << 16);
      *(uint2*)(prb + i4) = make_uint2(lo, hi);
    }
  }
}

// ---------------------------------------------------------------------------
// bf16 MFMA GEMM: async global_load_lds staging into fragment-ordered LDS
// (16-row group g -> contiguous 1KB block; both DMA and ds_read_b128 are
// contiguous, conflict-free). BK=64 (two MFMA sub-steps per barrier pair).
// VSPLIT (in_proj): cols >=512 (V) are written transposed to vt instead.
// ---------------------------------------------------------------------------
enum { EPI_NONE = 0, EPI_GELU = 1, EPI_ADDSCALE = 2 };

template <int EPI, int BM, int BN, bool OUTBF, bool VSPLIT>
__global__ __launch_bounds__(256, 4)
void mgemm(const u16* __restrict__ A, int lda,
           const u16* __restrict__ Wb, int K, const float* __restrict__ bias,
           void* __restrict__ Cv, int ldc, int col_off,
           const float* __restrict__ addsrc, u16* __restrict__ vt) {
  __shared__ u16 As[BM * 64];
  __shared__ u16 Bs[BN * 64];
  const int tid = threadIdx.x;
  const int w = tid >> 6, lane = tid & 63;
  const int ln = lane & 15, quad = lane >> 4;
  const int m0 = blockIdx.x * BM;
  const int n0 = blockIdx.y * BN;
  constexpr int MT = (BM == 128) ? 2 : 1;  // wave rows = 4 waves x (MT*16)
  const int wm = w * (MT * 16);
  constexpr int wn = 0;
  constexpr int APW = BM / 64;  // A 16-row groups per wave per sub-step
  constexpr int BPW = BN / 64;

  f32x4 acc[MT][4] = {};

  const int grow = lane >> 2;      // row within 16-row group
  const int gk8 = (lane & 3) * 8;  // k element offset

  for (int k0 = 0; k0 < K; k0 += 64) {
#pragma unroll
    for (int s = 0; s < 2; ++s) {
#pragma unroll
      for (int p = 0; p < APW; ++p) {
        const int g = w * APW + p;
        glds16(A + (size_t)(m0 + g * 16 + grow) * lda + k0 + s * 32 + gk8,
               As + s * BM * 32 + g * 512);
      }
#pragma unroll
      for (int p = 0; p < BPW; ++p) {
        const int g = w * BPW + p;
        glds16(Wb + (size_t)(n0 + g * 16 + grow) * K + k0 + s * 32 + gk8,
               Bs + s * BN * 32 + g * 512);
      }
    }
    __syncthreads();  // drains vmcnt -> LDS valid
#pragma unroll
    for (int s = 0; s < 2; ++s) {
      const u16* abase = As + s * BM * 32 + (wm >> 4) * 512 + ln * 32 + quad * 8;
      const u16* bbase = Bs + s * BN * 32 + ln * 32 + quad * 8;
      bf16x8 af[MT], bv[4];
#pragma unroll
      for (int i = 0; i < MT; ++i) af[i] = *(const bf16x8*)(abase + i * 512);
#pragma unroll
      for (int j = 0; j < 4; ++j) bv[j] = *(const bf16x8*)(bbase + j * 512);
#pragma unroll
      for (int i = 0; i < MT; ++i)
#pragma unroll
        for (int j = 0; j < 4; ++j)
          acc[i][j] = __builtin_amdgcn_mfma_f32_16x16x32_bf16(af[i], bv[j],
                                                              acc[i][j], 0, 0, 0);
    }
    __syncthreads();  // protect LDS reuse next iter
  }

#pragma unroll
  for (int i = 0; i < MT; ++i)
#pragma unroll
    for (int j = 0; j < 4; ++j) {
      const int col = n0 + wn + j * 16 + ln;
      const float bsv = bias[col];
      const int row0 = m0 + wm + i * 16 + quad * 4;
      float vals[4];
#pragma unroll
      for (int r = 0; r < 4; ++r) {
        float v = acc[i][j][r] + bsv;
        if (EPI == EPI_GELU) v = 0.5f * v * (1.0f + erff(v * 0.70710678f));
        if (EPI == EPI_ADDSCALE)
          v = addsrc[(size_t)(row0 + r) * 256 + col] + 0.3f * v;
        vals[r] = v;
      }
      if (VSPLIT && col >= 512) {
        // V: write transposed vt[(b*256 + (col-512))][t], 4 consecutive t
        ushort4 pk;
        pk.x = f2bf(vals[0]); pk.y = f2bf(vals[1]);
        pk.z = f2bf(vals[2]); pk.w = f2bf(vals[3]);
        *(ushort4*)(vt + (size_t)((row0 >> 10) * 256 + (col - 512)) * T_SZ +
                    (row0 & 1023)) = pk;
      } else if (OUTBF) {
#pragma unroll
        for (int r = 0; r < 4; ++r)
          ((u16*)Cv)[(size_t)(row0 + r) * ldc + col_off + col] = f2bf(vals[r]);
      } else {
#pragma unroll
        for (int r = 0; r < 4; ++r)
          ((float*)Cv)[(size_t)(row0 + r) * ldc + col_off + col] = vals[r];
      }
    }
}

// ---------------------------------------------------------------------------
// Barrier-free MFMA flash attention (one wave = 16 q rows, paired balance).
// ---------------------------------------------------------------------------
__global__ __launch_bounds__(256)
void attn_flash(const u16* __restrict__ qkv, const u16* __restrict__ vt,
                u16* __restrict__ outp) {
  __shared__ u16 Ps[4][16][72];
  const int tid = threadIdx.x;
  const int w = tid >> 6, lane = tid & 63;
  const int ln = lane & 15, quad = lane >> 4, kq8 = quad * 8;
  const int wu = blockIdx.x * 4 + w;
  const int bh = wu >> 6, s = wu & 63;
  const int qt = (s & 1) ? (63 - (s >> 1)) : (s >> 1);
  const int q0 = qt * 16;
  const int b = bh >> 2, h = bh & 3;
  const u16* base = qkv + (size_t)b * T_SZ * 768;
  const u16* vbase = vt + (size_t)bh * 64 * T_SZ;

  bf16x8 qf[2];
#pragma unroll
  for (int ks = 0; ks < 2; ++ks)
    qf[ks] = *(const bf16x8*)(base + (size_t)(q0 + ln) * 768 + h * 64 +
                              ks * 32 + kq8);
  const short ob = (short)0x3F80;
  const bf16x8 ones = {ob, ob, ob, ob, ob, ob, ob, ob};

  f32x4 O[4] = {};
  f32x4 l_acc = {};
  const int ntiles = (qt >> 2) + 1;
  for (int jt = 0; jt < ntiles; ++jt) {
    const int c0 = jt * 64;
    f32x4 sv[4] = {};
#pragma unroll
    for (int ks = 0; ks < 2; ++ks)
#pragma unroll
      for (int j = 0; j < 4; ++j) {
        bf16x8 kf = *(const bf16x8*)(base + (size_t)(c0 + j * 16 + ln) * 768 +
                                     256 + h * 64 + ks * 32 + kq8);
        sv[j] = __builtin_amdgcn_mfma_f32_16x16x32_bf16(qf[ks], kf, sv[j], 0, 0, 0);
      }
    const bool need_mask = (c0 + 63 > q0);
#pragma unroll
    for (int j = 0; j < 4; ++j)
#pragma unroll
      for (int r = 0; r < 4; ++r) {
        float p = __expf(sv[j][r] * 0.125f);
        if (need_mask && (c0 + j * 16 + ln > q0 + quad * 4 + r)) p = 0.f;
        Ps[w][quad * 4 + r][j * 16 + ln] = f2bf(p);
      }
#pragma unroll
    for (int ks = 0; ks < 2; ++ks) {
      bf16x8 pf = *(const bf16x8*)&Ps[w][ln][ks * 32 + kq8];
      l_acc = __builtin_amdgcn_mfma_f32_16x16x32_bf16(pf, ones, l_acc, 0, 0, 0);
#pragma unroll
      for (int j = 0; j < 4; ++j) {
        bf16x8 vf = *(const bf16x8*)(vbase + (size_t)(j * 16 + ln) * T_SZ +
                                     c0 + ks * 32 + kq8);
        O[j] = __builtin_amdgcn_mfma_f32_16x16x32_bf16(pf, vf, O[j], 0, 0, 0);
      }
    }
  }
  u16* op = outp + (size_t)b * T_SZ * 256;
#pragma unroll
  for (int r = 0; r < 4; ++r) {
    const float inv = 1.f / l_acc[r];
#pragma unroll
    for (int j = 0; j < 4; ++j)
      op[(size_t)(q0 + quad * 4 + r) * 256 + h * 64 + j * 16 + ln] =
          f2bf(O[j][r] * inv);
  }
}

// ---------------------------------------------------------------------------
// LayerNorm + misc elementwise (fp32 math)
// ---------------------------------------------------------------------------
__device__ __forceinline__ float block_reduce_sum(float v, float* tmp) {
#pragma unroll
  for (int o = 32; o > 0; o >>= 1) v += __shfl_down(v, o);
  const int lane = threadIdx.x & 63, wid = threadIdx.x >> 6;
  if (lane == 0) tmp[wid] = v;
  __syncthreads();
  v = tmp[0] + tmp[1] + tmp[2] + tmp[3];
  __syncthreads();
  return v;
}

__device__ __forceinline__ float ln_finish(float v, float s1, float s2,
                                           float g, float bb) {
  float mean = s1 * (1.f / 256.f);
  float var = s2 * (1.f / 256.f) - mean * mean;
  return (v - mean) * rsqrtf(var + 1e-5f) * g + bb;
}

__global__ __launch_bounds__(256)
void ln_add_kernel(const float* __restrict__ a, const float* __restrict__ addsrc,
                   const float* __restrict__ g, const float* __restrict__ bb,
                   float* __restrict__ outp, u16* __restrict__ obf) {
  __shared__ float tmp[4];
  const size_t row = blockIdx.x;
  const int d = threadIdx.x;
  float v = a[row * 256 + d] + addsrc[row * 256 + d];
  float s1 = block_reduce_sum(v, tmp);
  float s2 = block_reduce_sum(v * v, tmp);
  float y = ln_finish(v, s1, s2, g[d], bb[d]);
  outp[row * 256 + d] = y;
  if (obf) obf[row * 256 + d] = f2bf(y);
}

__global__ __launch_bounds__(256)
void ln3_states_kernel(const float* __restrict__ deltas, const float* __restrict__ scr,
                       const float* __restrict__ seq, const float* __restrict__ g,
                       const float* __restrict__ bb, u16* __restrict__ st) {
  __shared__ float tmp[4];
  const int row = blockIdx.x;
  const int b = row >> 10, t = row & 1023;
  const int d = threadIdx.x;
  float v = seq[b * 256 + d] +
            0.5f * (deltas[(size_t)row * 256 + d] +
                    scr[(size_t)(b * 32 + (t >> 5)) * 256 + d]);
  float s1 = block_reduce_sum(v, tmp);
  float s2 = block_reduce_sum(v * v, tmp);
  st[(size_t)row * 256 + d] = f2bf(ln_finish(v, s1, s2, g[d], bb[d]));
}

__global__ __launch_bounds__(256)
void ln4_kernel(const u16* __restrict__ st, const float* __restrict__ g,
                const float* __restrict__ bb, float* __restrict__ outp) {
  __shared__ float tmp[4];
  const int b = blockIdx.x, d = threadIdx.x;
  float v = bf2f(st[(size_t)(b * T_SZ + 1023) * 256 + d]);
  float s1 = block_reduce_sum(v, tmp);
  float s2 = block_reduce_sum(v * v, tmp);
  outp[b * 256 + d] = ln_finish(v, s1, s2, g[d], bb[d]);
}

// ---------------------------------------------------------------------------
// Fused depthwise conv (window 8) + EMA local pass.
// ---------------------------------------------------------------------------
__global__ __launch_bounds__(256)
void emaconv_kernel(const float* __restrict__ x, const float* __restrict__ cw,
                    const float* __restrict__ cb, u16* __restrict__ comb,
                    float* __restrict__ scr) {
  const int bc = blockIdx.x;
  const int b = bc >> 5, ch = bc & 31;
  const int d = threadIdx.x;
  const int t0 = ch * 32;
  float wreg[8];
#pragma unroll
  for (int j = 0; j < 8; ++j) wreg[j] = cw[d * 8 + j];
  const float bias = cb[d];
  float xw[8];
#pragma unroll
  for (int j = 0; j < 7; ++j) {
    const int ts = t0 - 7 + j;
    xw[j] = (ts >= 0) ? x[(size_t)(b * T_SZ + ts) * 256 + d] : 0.f;
  }
  float c = 0.f;
#pragma unroll
  for (int tl = 0; tl < 32; ++tl) {
    const size_t row = (size_t)(b * T_SZ + t0 + tl);
    xw[7] = x[row * 256 + d];
    float conv = bias;
#pragma unroll
    for (int j = 0; j < 8; ++j) conv = fmaf(xw[j], wreg[j], conv);
    c = 0.9f * c + 0.1f * xw[7];
    comb[row * 768 + 256 + d] = f2bf(conv);
    comb[row * 768 + 512 + d] = f2bf(c);
#pragma unroll
    for (int j = 0; j < 7; ++j) xw[j] = xw[j + 1];
  }
  scr[(size_t)bc * 256 + d] = c;
}

__global__ __launch_bounds__(256)
void ema_b_kernel(float* __restrict__ scr) {
  const int b = blockIdx.x, d = threadIdx.x;
  const float q32 = 0.03433683820292512f;  // 0.9^32
  float carry = 0.f;
  for (int ch = 0; ch < 32; ++ch) {
    const size_t idx = (size_t)(b * 32 + ch) * 256 + d;
    float e = scr[idx];
    scr[idx] = carry;
    carry = e + q32 * carry;
  }
}

__global__ __launch_bounds__(256)
void ema_c_kernel(u16* __restrict__ comb, const float* __restrict__ scr,
                  float* __restrict__ fts) {
  const int row = blockIdx.x;
  const int b = row >> 10, t = row & 1023;
  const int d = threadIdx.x;
  const int ch = t >> 5, tl = t & 31;
  float carry = scr[(size_t)(b * 32 + ch) * 256 + d];
  float l = bf2f(comb[(size_t)row * 768 + 512 + d]);
  float y = fmaf(__powf(0.9f, (float)(tl + 1)), carry, l);
  comb[(size_t)row * 768 + 512 + d] = f2bf(y);
  if (t == 1023) fts[b * 256 + d] = y;
}

__global__ __launch_bounds__(256)
void cs_a_kernel(float* __restrict__ deltas, float* __restrict__ scr) {
  const int bc = blockIdx.x;
  const int b = bc >> 5, ch = bc & 31;
  const int d = threadIdx.x;
  const int t0 = ch * 32;
  float c = 0.f;
  for (int tl = 0; tl < 32; ++tl) {
    const size_t idx = (size_t)(b * T_SZ + t0 + tl) * 256 + d;
    c += deltas[idx];
    deltas[idx] = c;
  }
  scr[(size_t)bc * 256 + d] = c;
}

__global__ __launch_bounds__(256)
void cs_b_kernel(float* __restrict__ scr) {
  const int b = blockIdx.x, d = threadIdx.x;
  float carry = 0.f;
  for (int ch = 0; ch < 32; ++ch) {
    const size_t idx = (size_t)(b * 32 + ch) * 256 + d;
    float e = scr[idx];
    scr[idx] = carry;
    carry += e;
  }
}

// ---------------------------------------------------------------------------
extern "C" void kernel_launch(void* const* d_in, const int* in_sizes, int n_in,
                              void* d_out, int out_size, void* d_ws,
                              size_t ws_size, hipStream_t stream) {
  (void)in_sizes; (void)n_in; (void)out_size; (void)ws_size;
  const float* parallel_repr = (const float*)d_in[0];
  const float* sequential_state = (const float*)d_in[1];
  const float* in_proj_b = (const float*)d_in[4];
  const float* out_proj_b = (const float*)d_in[6];
  const float* conv_w = (const float*)d_in[7];
  const float* conv_b = (const float*)d_in[8];
  const float* p2s_b = (const float*)d_in[10];
  const float* s2p_b = (const float*)d_in[12];
  const float* trans_b1 = (const float*)d_in[14];
  const float* trans_b2 = (const float*)d_in[16];
  const float* ffn_b1 = (const float*)d_in[18];
  const float* ffn_b2 = (const float*)d_in[20];
  const float* ln1_s = (const float*)d_in[21];
  const float* ln1_b = (const float*)d_in[22];
  const float* ln2_s = (const float*)d_in[23];
  const float* ln2_b = (const float*)d_in[24];
  const float* ln3_s = (const float*)d_in[25];
  const float* ln3_b = (const float*)d_in[26];
  const float* ln4_s = (const float*)d_in[27];
  const float* ln4_b = (const float*)d_in[28];

  char* ws = (char*)d_ws;
  u16* qkv_bf = (u16*)(ws + OFF_QKV);
  u16* attn_bf = (u16*)(ws + OFF_ATTN);
  u16* states_bf = (u16*)(ws + OFF_ATTN);
  u16* f_bf = (u16*)(ws + OFF_F);
  float* x = (float*)(ws + OFF_X);
  u16* comb = (u16*)(ws + OFF_COMB);
  u16* pr_bf = (u16*)(ws + OFF_COMB);  // dead before comb is written
  u16* ffn_in = (u16*)(ws + OFF_COMB); // overlay after comb consumed
  float* fbuf = (float*)(ws + OFF_FB);
  u16* vt = (u16*)(ws + OFF_H);        // dead before h is written
  u16* h_bf = (u16*)(ws + OFF_H);
  u16* x_bf = (u16*)(ws + OFF_XBF);
  u16* wb = (u16*)(ws + OFF_WB);
  float* scr1 = (float*)(ws + OFF_SCR1);
  float* scr2 = (float*)(ws + OFF_SCR2);
  float* out = (float*)d_out;
  float* out_fss = out + S_ELT;
  float* out_fts = out + S_ELT + 2048;

  const dim3 blk(256);

  // 0. weights + parallel_repr -> bf16
  wconv_kernel<<<3456, blk, 0, stream>>>(
      (const float*)d_in[3], (const float*)d_in[5], (const float*)d_in[9],
      (const float*)d_in[11], (const float*)d_in[13], (const float*)d_in[15],
      (const float*)d_in[17], (const float*)d_in[19], parallel_repr, wb, pr_bf);
  // 1. qkv = PR @ in_proj^T + b; V columns written transposed to vt
  mgemm<EPI_NONE, 128, 64, true, true><<<dim3(64, 12), blk, 0, stream>>>(
      pr_bf, 256, wb + WB_INPROJ, 256, in_proj_b, qkv_bf, 768, 0, nullptr, vt);
  // 2. attention (barrier-free)
  attn_flash<<<512, blk, 0, stream>>>(qkv_bf, vt, attn_bf);
  // 3. attn_out = attn @ out_proj^T + b -> fbuf (fp32)
  mgemm<EPI_NONE, 64, 64, false, false><<<dim3(128, 4), blk, 0, stream>>>(
      attn_bf, 256, wb + WB_OUTPROJ, 256, out_proj_b, fbuf, 256, 0, nullptr,
      nullptr);
  // 4. x = LN1(PR + attn_out), also emit x_bf
  ln_add_kernel<<<8192, blk, 0, stream>>>(parallel_repr, fbuf, ln1_s, ln1_b, x,
                                          x_bf);
  // 5-7. fused conv+EMA -> comb[:,256:768] + traj summary
  emaconv_kernel<<<256, blk, 0, stream>>>(x, conv_w, conv_b, comb, scr1);
  ema_b_kernel<<<8, blk, 0, stream>>>(scr1);
  ema_c_kernel<<<8192, blk, 0, stream>>>(comb, scr1, out_fts);
  // 8. comb[:,0:256] = x + 0.3*(x @ p2s^T + b)
  mgemm<EPI_ADDSCALE, 64, 64, true, false><<<dim3(128, 4), blk, 0, stream>>>(
      x_bf, 256, wb + WB_P2S, 256, p2s_b, comb, 768, 0, x, nullptr);
  // 9. h = gelu(comb @ t1^T + b1)
  mgemm<EPI_GELU, 128, 64, true, false><<<dim3(64, 8), blk, 0, stream>>>(
      comb, 768, wb + WB_T1, 768, trans_b1, h_bf, 512, 0, nullptr, nullptr);
  // 10. deltas = h @ t2^T + b2 -> fbuf (fp32)
  mgemm<EPI_NONE, 64, 64, false, false><<<dim3(128, 4), blk, 0, stream>>>(
      h_bf, 512, wb + WB_T2, 512, trans_b2, fbuf, 256, 0, nullptr, nullptr);
  // 11-12. cumsum
  cs_a_kernel<<<256, blk, 0, stream>>>(fbuf, scr2);
  cs_b_kernel<<<8, blk, 0, stream>>>(scr2);
  // 13. states = LN3(...) -> bf16
  ln3_states_kernel<<<8192, blk, 0, stream>>>(fbuf, scr2, sequential_state,
                                              ln3_s, ln3_b, states_bf);
  // 14. fss = LN4(states[:,-1])
  ln4_kernel<<<8, blk, 0, stream>>>(states_bf, ln4_s, ln4_b, out_fss);
  // 15. ffn_in = x + 0.3*(states @ s2p^T + b)
  mgemm<EPI_ADDSCALE, 64, 64, true, false><<<dim3(128, 4), blk, 0, stream>>>(
      states_bf, 256, wb + WB_S2P, 256, s2p_b, ffn_in, 256, 0, x, nullptr);
  // 16. f = gelu(ffn_in @ ffn1^T + b1)
  mgemm<EPI_GELU, 128, 64, true, false><<<dim3(64, 16), blk, 0, stream>>>(
      ffn_in, 256, wb + WB_F1, 256, ffn_b1, f_bf, 1024, 0, nullptr, nullptr);
  // 17. ffn_out = f @ ffn2^T + b2 -> fbuf
  mgemm<EPI_NONE, 64, 64, false, false><<<dim3(128, 4), blk, 0, stream>>>(
      f_bf, 1024, wb + WB_F2, 1024, ffn_b2, fbuf, 256, 0, nullptr, nullptr);
  // 18. out = LN2(x + ffn_out)
  ln_add_kernel<<<8192, blk, 0, stream>>>(x, fbuf, ln2_s, ln2_b, out, nullptr);
}